// Round 1
// baseline (2539.436 us; speedup 1.0000x reference)
//
#include <hip/hip_runtime.h>
#include <hip/hip_bf16.h>
#include <cmath>

#define BATCH 32
#define H_IN 56
#define W_IN 56
#define N_IN (H_IN * W_IN)   // 3136
#define C 96
#define HP 28
#define LKV (HP * HP)        // 784
#define KB 16                // K/V rows per LDS tile in attention

// ---------------------------------------------------------------------------
// GEMM, one thread per token. X: [T][96] fp32. W: [E][96] row-major.
// E is processed in chunks of 96 rows staged in LDS (broadcast reads).
// chunk c writes to out_c (qkv split falls out naturally: q, k, v chunks).
// ---------------------------------------------------------------------------
__global__ __launch_bounds__(256) void gemm_tok_kernel(
    const float* __restrict__ X, const float* __restrict__ W,
    const float* __restrict__ bias, float* __restrict__ out0,
    float* __restrict__ out1, float* __restrict__ out2, int nchunks)
{
    __shared__ float4 Ws[96 * 24];   // one 96x96 fp32 chunk = 36 KB
    const int token = blockIdx.x * 256 + threadIdx.x;

    // x row into registers (24 float4 = 96 floats)
    float4 xr[24];
    const float4* xg = reinterpret_cast<const float4*>(X + (size_t)token * 96);
#pragma unroll
    for (int i = 0; i < 24; ++i) xr[i] = xg[i];

    for (int c = 0; c < nchunks; ++c) {
        __syncthreads();
        const float4* wg = reinterpret_cast<const float4*>(W + (size_t)c * 96 * 96);
#pragma unroll
        for (int i = 0; i < 9; ++i)
            Ws[threadIdx.x + 256 * i] = wg[threadIdx.x + 256 * i];
        __syncthreads();

        float* outp = (c == 0) ? out0 : ((c == 1) ? out1 : out2);
        float4* op = reinterpret_cast<float4*>(outp + (size_t)token * 96);
        const float* bp = bias + c * 96;

        for (int e4 = 0; e4 < 24; ++e4) {
            float a0 = bp[e4 * 4 + 0];
            float a1 = bp[e4 * 4 + 1];
            float a2 = bp[e4 * 4 + 2];
            float a3 = bp[e4 * 4 + 3];
            const float4* w0 = &Ws[(e4 * 4 + 0) * 24];
            const float4* w1 = &Ws[(e4 * 4 + 1) * 24];
            const float4* w2 = &Ws[(e4 * 4 + 2) * 24];
            const float4* w3 = &Ws[(e4 * 4 + 3) * 24];
#pragma unroll
            for (int k = 0; k < 24; ++k) {
                float4 xv = xr[k];
                float4 v0 = w0[k];
                a0 += xv.x * v0.x + xv.y * v0.y + xv.z * v0.z + xv.w * v0.w;
                float4 v1 = w1[k];
                a1 += xv.x * v1.x + xv.y * v1.y + xv.z * v1.z + xv.w * v1.w;
                float4 v2 = w2[k];
                a2 += xv.x * v2.x + xv.y * v2.y + xv.z * v2.z + xv.w * v2.w;
                float4 v3 = w3[k];
                a3 += xv.x * v3.x + xv.y * v3.y + xv.z * v3.z + xv.w * v3.w;
            }
            op[e4] = make_float4(a0, a1, a2, a3);
        }
    }
}

// ---------------------------------------------------------------------------
// Depthwise 3x3 conv (padding 1, given stride) + LayerNorm over C=96.
// One block (96 threads) per output token. grid = (Wp, Hp, B).
// in: [B][56*56][96], out: [B][Hp*Wp][96]
// ---------------------------------------------------------------------------
__global__ __launch_bounds__(96) void pool_ln_kernel(
    const float* __restrict__ in, const float* __restrict__ wconv,
    const float* __restrict__ g, const float* __restrict__ beta,
    float* __restrict__ out, int stride, int Hp, int Wp)
{
    const int c = threadIdx.x;           // 0..95
    const int xo = blockIdx.x;
    const int yo = blockIdx.y;
    const int b  = blockIdx.z;

    float wv[9];
#pragma unroll
    for (int t = 0; t < 9; ++t) wv[t] = wconv[c * 9 + t];

    float v = 0.f;
#pragma unroll
    for (int ky = 0; ky < 3; ++ky) {
        int iy = yo * stride + ky - 1;
        if ((unsigned)iy < (unsigned)H_IN) {
#pragma unroll
            for (int kx = 0; kx < 3; ++kx) {
                int ix = xo * stride + kx - 1;
                if ((unsigned)ix < (unsigned)W_IN) {
                    v += wv[ky * 3 + kx] *
                         in[(((size_t)b * H_IN + iy) * W_IN + ix) * 96 + c];
                }
            }
        }
    }

    // LayerNorm over the 96 channels of this token
    __shared__ float s1[96], s2[96];
    __shared__ float red[2];
    s1[c] = v;
    s2[c] = v * v;
    __syncthreads();
    if (c < 32) {
        float a = s1[c] + s1[c + 32] + s1[c + 64];
        float q = s2[c] + s2[c + 32] + s2[c + 64];
#pragma unroll
        for (int off = 16; off >= 1; off >>= 1) {
            a += __shfl_down(a, off, 32);
            q += __shfl_down(q, off, 32);
        }
        if (c == 0) { red[0] = a; red[1] = q; }
    }
    __syncthreads();
    float mu = red[0] * (1.f / 96.f);
    float var = red[1] * (1.f / 96.f) - mu * mu;
    float rstd = rsqrtf(var + 1e-6f);

    out[(((size_t)b * Hp + yo) * Wp + xo) * 96 + c] = (v - mu) * rstd * g[c] + beta[c];
}

// ---------------------------------------------------------------------------
// Flash-style attention + residual. One wave (64 threads) per 64 Q-rows.
// Each lane owns one Q row: q[96] and acc[96] in registers, K/V tiles (16
// rows) staged in LDS and read wave-uniform (broadcast). Online softmax in
// log2 domain; rescale only when the running max changes (wave-uniform test).
// out[row] = softmax(q*scale @ K^T) @ V + q
// ---------------------------------------------------------------------------
__global__ __launch_bounds__(64, 1) void attn_kernel(
    const float* __restrict__ qp, const float* __restrict__ kp,
    const float* __restrict__ vp, float* __restrict__ out)
{
    __shared__ float4 Ks[KB * 24], Vs[KB * 24];
    const int lane = threadIdx.x;
    const int row = blockIdx.x * 64 + lane;
    const int b = blockIdx.y;

    const float4* qg = reinterpret_cast<const float4*>(qp + ((size_t)b * N_IN + row) * 96);
    float4 qv[24];
#pragma unroll
    for (int i = 0; i < 24; ++i) qv[i] = qg[i];
    float4 av[24];
#pragma unroll
    for (int i = 0; i < 24; ++i) av[i] = make_float4(0.f, 0.f, 0.f, 0.f);

    // scale * log2(e): softmax computed with exp2
    const float SCALE2 = 0.1020620726159658f * 1.4426950408889634f;
    float m2 = -INFINITY, l = 0.f;

    const float4* kg = reinterpret_cast<const float4*>(kp + (size_t)b * LKV * 96);
    const float4* vg = reinterpret_cast<const float4*>(vp + (size_t)b * LKV * 96);

    for (int jc = 0; jc < LKV / KB; ++jc) {
        __syncthreads();
#pragma unroll
        for (int i = 0; i < 6; ++i) {
            Ks[lane + 64 * i] = kg[jc * (KB * 24) + lane + 64 * i];
            Vs[lane + 64 * i] = vg[jc * (KB * 24) + lane + 64 * i];
        }
        __syncthreads();

        for (int j = 0; j < KB; ++j) {
            const float4* kr = Ks + j * 24;
            float s = 0.f;
#pragma unroll
            for (int k = 0; k < 24; ++k) {
                float4 kvv = kr[k];
                float4 xv = qv[k];
                s += xv.x * kvv.x + xv.y * kvv.y + xv.z * kvv.z + xv.w * kvv.w;
            }
            s *= SCALE2;

            if (__any(s > m2)) {          // wave-uniform deferred rescale
                float mn = fmaxf(m2, s);
                float corr = exp2f(m2 - mn);   // exp2f(-inf)=0 handles init
                l *= corr;
#pragma unroll
                for (int k = 0; k < 24; ++k) {
                    av[k].x *= corr; av[k].y *= corr;
                    av[k].z *= corr; av[k].w *= corr;
                }
                m2 = mn;
            }
            float p = exp2f(s - m2);
            l += p;
            const float4* vr = Vs + j * 24;
#pragma unroll
            for (int k = 0; k < 24; ++k) {
                float4 vvv = vr[k];
                av[k].x += p * vvv.x; av[k].y += p * vvv.y;
                av[k].z += p * vvv.z; av[k].w += p * vvv.w;
            }
        }
    }

    const float inv = 1.f / l;
    float4* og = reinterpret_cast<float4*>(out + ((size_t)b * N_IN + row) * 96);
#pragma unroll
    for (int k = 0; k < 24; ++k) {
        float4 o;
        o.x = av[k].x * inv + qv[k].x;
        o.y = av[k].y * inv + qv[k].y;
        o.z = av[k].z * inv + qv[k].z;
        o.w = av[k].w * inv + qv[k].w;
        og[k] = o;
    }
}

// ---------------------------------------------------------------------------
extern "C" void kernel_launch(void* const* d_in, const int* in_sizes, int n_in,
                              void* d_out, int out_size, void* d_ws, size_t ws_size,
                              hipStream_t stream)
{
    const float* x     = (const float*)d_in[0];
    const float* Wqkv  = (const float*)d_in[1];
    const float* bqkv  = (const float*)d_in[2];
    const float* pqw   = (const float*)d_in[3];
    const float* gq    = (const float*)d_in[4];
    const float* betq  = (const float*)d_in[5];
    const float* pkw   = (const float*)d_in[6];
    const float* gk    = (const float*)d_in[7];
    const float* betk  = (const float*)d_in[8];
    const float* pvw   = (const float*)d_in[9];
    const float* gv    = (const float*)d_in[10];
    const float* betv  = (const float*)d_in[11];
    const float* Wproj = (const float*)d_in[12];
    const float* bproj = (const float*)d_in[13];
    float* outp = (float*)d_out;

    char* ws = (char*)d_ws;
    const size_t FULL = (size_t)BATCH * N_IN * 96 * sizeof(float);  // 38.5 MB
    const size_t PB   = (size_t)BATCH * LKV * 96 * sizeof(float);   // 9.6 MB
    float* qf  = (float*)(ws);
    float* kf  = (float*)(ws + FULL);
    float* vf  = (float*)(ws + 2 * FULL);
    float* qpb = (float*)(ws + 3 * FULL);
    float* kpb = (float*)(ws + 4 * FULL);
    float* vpb = (float*)(ws + 4 * FULL + PB);
    float* attn_out = qf;   // q_full dead after pool_q; reuse for attention out

    const int T = BATCH * N_IN;   // 100352 tokens

    // 1. QKV projection -> q_full, k_full, v_full
    gemm_tok_kernel<<<T / 256, 256, 0, stream>>>(x, Wqkv, bqkv, qf, kf, vf, 3);
    // 2-4. depthwise conv + LN pools
    pool_ln_kernel<<<dim3(56, 56, BATCH), 96, 0, stream>>>(qf, pqw, gq, betq, qpb, 1, 56, 56);
    pool_ln_kernel<<<dim3(28, 28, BATCH), 96, 0, stream>>>(kf, pkw, gk, betk, kpb, 2, 28, 28);
    pool_ln_kernel<<<dim3(28, 28, BATCH), 96, 0, stream>>>(vf, pvw, gv, betv, vpb, 2, 28, 28);
    // 5. attention + residual
    attn_kernel<<<dim3(N_IN / 64, BATCH), 64, 0, stream>>>(qpb, kpb, vpb, attn_out);
    // 6. output projection
    gemm_tok_kernel<<<T / 256, 256, 0, stream>>>(attn_out, Wproj, bproj, outp, nullptr, nullptr, 1);
}

// Round 2
// 720.355 us; speedup vs baseline: 3.5253x; 3.5253x over previous
//
#include <hip/hip_runtime.h>
#include <hip/hip_bf16.h>
#include <cmath>
#include <cstring>

#define BATCH 32
#define H_IN 56
#define W_IN 56
#define N_IN (H_IN * W_IN)   // 3136
#define C 96
#define HP 28
#define LKV (HP * HP)        // 784
#define KVB 112              // kv rows per attention LDS tile (784 = 7*112)
#define KLDS_W 104           // padded K-tile row stride (bf16 elems)
#define VLDS_W 136           // padded V^T-tile row stride (bf16 elems)

typedef short bf16x8 __attribute__((ext_vector_type(8)));
typedef float f32x4 __attribute__((ext_vector_type(4)));

__device__ __forceinline__ unsigned pack_bf16(float a, float b) {
    unsigned ua = __builtin_bit_cast(unsigned, a);
    unsigned ub = __builtin_bit_cast(unsigned, b);
    ua = (ua + 0x7FFFu + ((ua >> 16) & 1u)) >> 16;
    ub = (ub + 0x7FFFu + ((ub >> 16) & 1u)) >> 16;
    return ua | (ub << 16);
}

__device__ __forceinline__ unsigned short cvt_bf16(float a) {
    unsigned ua = __builtin_bit_cast(unsigned, a);
    return (unsigned short)((ua + 0x7FFFu + ((ua >> 16) & 1u)) >> 16);
}

__device__ __forceinline__ float bf16_to_f32(unsigned short u) {
    unsigned v = ((unsigned)u) << 16;
    return __builtin_bit_cast(float, v);
}

// ---------------------------------------------------------------------------
// GEMM, one thread per token. X: [T][96] fp32. W: [E][96] row-major.
// ---------------------------------------------------------------------------
__global__ __launch_bounds__(256) void gemm_tok_kernel(
    const float* __restrict__ X, const float* __restrict__ W,
    const float* __restrict__ bias, float* __restrict__ out0,
    float* __restrict__ out1, float* __restrict__ out2, int nchunks)
{
    __shared__ float4 Ws[96 * 24];   // one 96x96 fp32 chunk = 36 KB
    const int token = blockIdx.x * 256 + threadIdx.x;

    float4 xr[24];
    const float4* xg = reinterpret_cast<const float4*>(X + (size_t)token * 96);
#pragma unroll
    for (int i = 0; i < 24; ++i) xr[i] = xg[i];

    for (int c = 0; c < nchunks; ++c) {
        __syncthreads();
        const float4* wg = reinterpret_cast<const float4*>(W + (size_t)c * 96 * 96);
#pragma unroll
        for (int i = 0; i < 9; ++i)
            Ws[threadIdx.x + 256 * i] = wg[threadIdx.x + 256 * i];
        __syncthreads();

        float* outp = (c == 0) ? out0 : ((c == 1) ? out1 : out2);
        float4* op = reinterpret_cast<float4*>(outp + (size_t)token * 96);
        const float* bp = bias + c * 96;

        for (int e4 = 0; e4 < 24; ++e4) {
            float a0 = bp[e4 * 4 + 0];
            float a1 = bp[e4 * 4 + 1];
            float a2 = bp[e4 * 4 + 2];
            float a3 = bp[e4 * 4 + 3];
            const float4* w0 = &Ws[(e4 * 4 + 0) * 24];
            const float4* w1 = &Ws[(e4 * 4 + 1) * 24];
            const float4* w2 = &Ws[(e4 * 4 + 2) * 24];
            const float4* w3 = &Ws[(e4 * 4 + 3) * 24];
#pragma unroll
            for (int k = 0; k < 24; ++k) {
                float4 xv = xr[k];
                float4 v0 = w0[k];
                a0 += xv.x * v0.x + xv.y * v0.y + xv.z * v0.z + xv.w * v0.w;
                float4 v1 = w1[k];
                a1 += xv.x * v1.x + xv.y * v1.y + xv.z * v1.z + xv.w * v1.w;
                float4 v2 = w2[k];
                a2 += xv.x * v2.x + xv.y * v2.y + xv.z * v2.z + xv.w * v2.w;
                float4 v3 = w3[k];
                a3 += xv.x * v3.x + xv.y * v3.y + xv.z * v3.z + xv.w * v3.w;
            }
            op[e4] = make_float4(a0, a1, a2, a3);
        }
    }
}

// ---------------------------------------------------------------------------
// Depthwise 3x3 conv (pad 1, stride) + LayerNorm over C=96 -> bf16 output.
// TRANSPOSED=false: out [B][Lp][96]; TRANSPOSED=true: out [B][96][Lp].
// ---------------------------------------------------------------------------
template <bool TRANSPOSED>
__global__ __launch_bounds__(96) void pool_ln_kernel(
    const float* __restrict__ in, const float* __restrict__ wconv,
    const float* __restrict__ g, const float* __restrict__ beta,
    unsigned short* __restrict__ out, int stride, int Hp, int Wp)
{
    const int c = threadIdx.x;           // 0..95
    const int xo = blockIdx.x;
    const int yo = blockIdx.y;
    const int b  = blockIdx.z;

    float wv[9];
#pragma unroll
    for (int t = 0; t < 9; ++t) wv[t] = wconv[c * 9 + t];

    float v = 0.f;
#pragma unroll
    for (int ky = 0; ky < 3; ++ky) {
        int iy = yo * stride + ky - 1;
        if ((unsigned)iy < (unsigned)H_IN) {
#pragma unroll
            for (int kx = 0; kx < 3; ++kx) {
                int ix = xo * stride + kx - 1;
                if ((unsigned)ix < (unsigned)W_IN) {
                    v += wv[ky * 3 + kx] *
                         in[(((size_t)b * H_IN + iy) * W_IN + ix) * 96 + c];
                }
            }
        }
    }

    __shared__ float s1[96], s2[96];
    __shared__ float red[2];
    s1[c] = v;
    s2[c] = v * v;
    __syncthreads();
    if (c < 32) {
        float a = s1[c] + s1[c + 32] + s1[c + 64];
        float q = s2[c] + s2[c + 32] + s2[c + 64];
#pragma unroll
        for (int off = 16; off >= 1; off >>= 1) {
            a += __shfl_down(a, off, 32);
            q += __shfl_down(q, off, 32);
        }
        if (c == 0) { red[0] = a; red[1] = q; }
    }
    __syncthreads();
    float mu = red[0] * (1.f / 96.f);
    float var = red[1] * (1.f / 96.f) - mu * mu;
    float rstd = rsqrtf(var + 1e-6f);
    float r = (v - mu) * rstd * g[c] + beta[c];

    const int tok = yo * Wp + xo;
    const int Lp = Hp * Wp;
    if (TRANSPOSED)
        out[((size_t)b * 96 + c) * Lp + tok] = cvt_bf16(r);
    else
        out[((size_t)b * Lp + tok) * 96 + c] = cvt_bf16(r);
}

// ---------------------------------------------------------------------------
// MFMA flash attention + residual.
// 256 threads = 4 waves; each wave owns 16 q rows (block: 64 q rows).
// Swapped QK^T: S^T = mfma(A=K_tile, B=Q^T) -> lane holds 4 kv-values for
// one q (q = lane&15). Online softmax lane-local; row reduce = 2 shfl_xor.
// Swapped PV: O^T += mfma(A=V^T_tile, B=P^T); P^T B-frag built in-register
// via __shfl redistribution. Epilogue: O/l + q residual, fp32 store.
// q: bf16 [B][3136][96]; k: bf16 [B][784][96]; vT: bf16 [B][96][784].
// ---------------------------------------------------------------------------
__global__ __launch_bounds__(256, 3) void attn_mfma_kernel(
    const unsigned short* __restrict__ qb, const unsigned short* __restrict__ kb,
    const unsigned short* __restrict__ vtb, float* __restrict__ out)
{
    __shared__ unsigned short Kl[KVB * KLDS_W];   // 23296 B
    __shared__ unsigned short Vt[96 * VLDS_W];    // 26112 B

    const int tid = threadIdx.x;
    const int wid = tid >> 6;
    const int lane = tid & 63;
    const int lo16 = lane & 15;
    const int hi = lane >> 4;          // 0..3
    const int b = blockIdx.y;
    const int qrow = blockIdx.x * 64 + wid * 16 + lo16;

    // zero-fill V^T pad columns 112..127 (partial PV k-step reads them)
    for (int i = tid; i < 192; i += 256) {
        int row = i >> 1, col = 112 + (i & 1) * 8;
        *reinterpret_cast<int4*>(&Vt[row * VLDS_W + col]) = make_int4(0, 0, 0, 0);
    }

    // Q fragments (B-operand of S^T mfma): Q[q=lo16][k = ks*32 + hi*8 + i]
    bf16x8 qfrag[3];
    const unsigned short* qr = qb + ((size_t)b * N_IN + qrow) * 96;
#pragma unroll
    for (int ks = 0; ks < 3; ++ks)
        qfrag[ks] = *reinterpret_cast<const bf16x8*>(qr + ks * 32 + hi * 8);

    f32x4 acc[6];
#pragma unroll
    for (int mt = 0; mt < 6; ++mt) acc[mt] = (f32x4){0.f, 0.f, 0.f, 0.f};
    float m = -INFINITY, l = 0.f;

    const float SC = 0.1020620726159658f * 1.4426950408889634f; // scale*log2e
    const unsigned short* kg0 = kb + (size_t)b * LKV * 96;
    const unsigned short* vg0 = vtb + (size_t)b * 96 * LKV;

    for (int t = 0; t < 7; ++t) {
        __syncthreads();
        // stage K tile [112][96] -> Kl (padded rows)
        const unsigned short* kg = kg0 + (size_t)t * KVB * 96;
        for (int i = tid; i < 1344; i += 256) {
            int r = i / 12, cc = i % 12;
            *reinterpret_cast<int4*>(&Kl[r * KLDS_W + cc * 8]) =
                *reinterpret_cast<const int4*>(kg + r * 96 + cc * 8);
        }
        // stage V^T tile [96][112] -> Vt (padded rows)
        const unsigned short* vg = vg0 + t * KVB;
        for (int i = tid; i < 1344; i += 256) {
            int r = i / 14, cc = i % 14;
            *reinterpret_cast<int4*>(&Vt[r * VLDS_W + cc * 8]) =
                *reinterpret_cast<const int4*>(vg + (size_t)r * LKV + cc * 8);
        }
        __syncthreads();

        // S^T tiles: 7 x (16 kv x 16 q), each 3 mfma over k=96
        f32x4 st[7];
#pragma unroll
        for (int tt = 0; tt < 7; ++tt) {
            f32x4 s = (f32x4){0.f, 0.f, 0.f, 0.f};
#pragma unroll
            for (int ks = 0; ks < 3; ++ks) {
                bf16x8 af = *reinterpret_cast<const bf16x8*>(
                    &Kl[(tt * 16 + lo16) * KLDS_W + ks * 32 + hi * 8]);
                s = __builtin_amdgcn_mfma_f32_16x16x32_bf16(af, qfrag[ks], s, 0, 0, 0);
            }
#pragma unroll
            for (int r = 0; r < 4; ++r) s[r] *= SC;
            st[tt] = s;
        }

        // row max across kv (per q): in-lane then across hi via shfl_xor
        float tm = st[0][0];
#pragma unroll
        for (int tt = 0; tt < 7; ++tt)
#pragma unroll
            for (int r = 0; r < 4; ++r) tm = fmaxf(tm, st[tt][r]);
        tm = fmaxf(tm, __shfl_xor(tm, 16));
        tm = fmaxf(tm, __shfl_xor(tm, 32));

        float mnew = fmaxf(m, tm);
        float corr = exp2f(m - mnew);   // exp2f(-inf)=0 handles first tile
        m = mnew;
        l *= corr;
#pragma unroll
        for (int mt = 0; mt < 6; ++mt)
#pragma unroll
            for (int r = 0; r < 4; ++r) acc[mt][r] *= corr;

        // p = exp2(s - m); accumulate l; pack to bf16 pairs
        unsigned pk0[7], pk1[7];
        float ls = 0.f;
#pragma unroll
        for (int tt = 0; tt < 7; ++tt) {
            float p0 = exp2f(st[tt][0] - m);
            float p1 = exp2f(st[tt][1] - m);
            float p2 = exp2f(st[tt][2] - m);
            float p3 = exp2f(st[tt][3] - m);
            ls += (p0 + p1) + (p2 + p3);
            pk0[tt] = pack_bf16(p0, p1);
            pk1[tt] = pack_bf16(p2, p3);
        }
        l += ls;

        // PV: O^T += V^T * P^T   (4 k-steps of 32 kv; last is partial/padded)
        const int src0 = lo16 + ((hi & 1) ? 32 : 0);
        const int src1 = src0 + 16;
        const bool up = (hi & 2);
#pragma unroll
        for (int ks = 0; ks < 4; ++ks) {
            unsigned w0, w1, w2, w3;
            {
                unsigned a0 = __shfl(pk0[2 * ks], src0);
                unsigned a1 = __shfl(pk1[2 * ks], src0);
                unsigned a2 = __shfl(pk0[2 * ks], src1);
                unsigned a3 = __shfl(pk1[2 * ks], src1);
                if (ks < 3) {
                    unsigned b0 = __shfl(pk0[2 * ks + 1], src0);
                    unsigned b1 = __shfl(pk1[2 * ks + 1], src0);
                    unsigned b2 = __shfl(pk0[2 * ks + 1], src1);
                    unsigned b3 = __shfl(pk1[2 * ks + 1], src1);
                    w0 = up ? b0 : a0; w1 = up ? b1 : a1;
                    w2 = up ? b2 : a2; w3 = up ? b3 : a3;
                } else {
                    w0 = up ? 0u : a0; w1 = up ? 0u : a1;
                    w2 = up ? 0u : a2; w3 = up ? 0u : a3;
                }
            }
            int4 bw = make_int4((int)w0, (int)w1, (int)w2, (int)w3);
            bf16x8 bfrag = __builtin_bit_cast(bf16x8, bw);
#pragma unroll
            for (int mt = 0; mt < 6; ++mt) {
                bf16x8 af = *reinterpret_cast<const bf16x8*>(
                    &Vt[(mt * 16 + lo16) * VLDS_W + ks * 32 + hi * 8]);
                acc[mt] = __builtin_amdgcn_mfma_f32_16x16x32_bf16(af, bfrag, acc[mt], 0, 0, 0);
            }
        }
    }

    // final l reduce across the 4 lane-groups sharing this q
    l += __shfl_xor(l, 16);
    l += __shfl_xor(l, 32);
    const float inv = 1.f / l;

    // epilogue: out[q][ch] = acc/l + q_residual ; ch = mt*16 + hi*4 + r
    float* op = out + ((size_t)b * N_IN + qrow) * 96;
#pragma unroll
    for (int mt = 0; mt < 6; ++mt) {
        int ch = mt * 16 + hi * 4;
        ushort4 qres = *reinterpret_cast<const ushort4*>(qr + ch);
        float4 o;
        o.x = acc[mt][0] * inv + bf16_to_f32(qres.x);
        o.y = acc[mt][1] * inv + bf16_to_f32(qres.y);
        o.z = acc[mt][2] * inv + bf16_to_f32(qres.z);
        o.w = acc[mt][3] * inv + bf16_to_f32(qres.w);
        *reinterpret_cast<float4*>(op + ch) = o;
    }
}

// ---------------------------------------------------------------------------
extern "C" void kernel_launch(void* const* d_in, const int* in_sizes, int n_in,
                              void* d_out, int out_size, void* d_ws, size_t ws_size,
                              hipStream_t stream)
{
    const float* x     = (const float*)d_in[0];
    const float* Wqkv  = (const float*)d_in[1];
    const float* bqkv  = (const float*)d_in[2];
    const float* pqw   = (const float*)d_in[3];
    const float* gq    = (const float*)d_in[4];
    const float* betq  = (const float*)d_in[5];
    const float* pkw   = (const float*)d_in[6];
    const float* gk    = (const float*)d_in[7];
    const float* betk  = (const float*)d_in[8];
    const float* pvw   = (const float*)d_in[9];
    const float* gv    = (const float*)d_in[10];
    const float* betv  = (const float*)d_in[11];
    const float* Wproj = (const float*)d_in[12];
    const float* bproj = (const float*)d_in[13];
    float* outp = (float*)d_out;

    char* ws = (char*)d_ws;
    const size_t FULL  = (size_t)BATCH * N_IN * 96 * sizeof(float);      // 38.5 MB
    const size_t QB    = (size_t)BATCH * N_IN * 96 * sizeof(short);      // 19.3 MB
    const size_t KVBYT = (size_t)BATCH * LKV * 96 * sizeof(short);       // 4.8 MB
    float* qf = (float*)(ws);
    float* kf = (float*)(ws + FULL);
    float* vf = (float*)(ws + 2 * FULL);
    unsigned short* qpb  = (unsigned short*)(ws + 3 * FULL);
    unsigned short* kpb  = (unsigned short*)(ws + 3 * FULL + QB);
    unsigned short* vptb = (unsigned short*)(ws + 3 * FULL + QB + KVBYT);
    float* attn_out = qf;   // q_full dead after pool_q

    const int T = BATCH * N_IN;

    // 1. QKV projection -> q_full, k_full, v_full (fp32)
    gemm_tok_kernel<<<T / 256, 256, 0, stream>>>(x, Wqkv, bqkv, qf, kf, vf, 3);
    // 2-4. depthwise conv + LN pools -> bf16 (v transposed)
    pool_ln_kernel<false><<<dim3(56, 56, BATCH), 96, 0, stream>>>(qf, pqw, gq, betq, qpb, 1, 56, 56);
    pool_ln_kernel<false><<<dim3(28, 28, BATCH), 96, 0, stream>>>(kf, pkw, gk, betk, kpb, 2, 28, 28);
    pool_ln_kernel<true ><<<dim3(28, 28, BATCH), 96, 0, stream>>>(vf, pvw, gv, betv, vptb, 2, 28, 28);
    // 5. MFMA attention + residual (fp32 out)
    attn_mfma_kernel<<<dim3(N_IN / 64, BATCH), 256, 0, stream>>>(qpb, kpb, vptb, attn_out);
    // 6. output projection
    gemm_tok_kernel<<<T / 256, 256, 0, stream>>>(attn_out, Wproj, bproj, outp, nullptr, nullptr, 1);
}

// Round 3
// 335.273 us; speedup vs baseline: 7.5742x; 2.1486x over previous
//
#include <hip/hip_runtime.h>
#include <hip/hip_bf16.h>
#include <cmath>
#include <cstring>

#define BATCH 32
#define H_IN 56
#define W_IN 56
#define N_IN (H_IN * W_IN)   // 3136
#define C 96
#define HP 28
#define LKV (HP * HP)        // 784
#define KVB 112              // kv rows per attention LDS tile (784 = 7*112)
#define KLDS_W 104           // padded K-tile row stride (bf16 elems)
#define VLDS_W 136           // padded V^T-tile row stride (bf16 elems)

typedef short bf16x8 __attribute__((ext_vector_type(8)));
typedef float f32x4 __attribute__((ext_vector_type(4)));

__device__ __forceinline__ unsigned pack_bf16(float a, float b) {
    unsigned ua = __builtin_bit_cast(unsigned, a);
    unsigned ub = __builtin_bit_cast(unsigned, b);
    ua = (ua + 0x7FFFu + ((ua >> 16) & 1u)) >> 16;
    ub = (ub + 0x7FFFu + ((ub >> 16) & 1u)) >> 16;
    return ua | (ub << 16);
}

__device__ __forceinline__ unsigned short cvt_bf16(float a) {
    unsigned ua = __builtin_bit_cast(unsigned, a);
    return (unsigned short)((ua + 0x7FFFu + ((ua >> 16) & 1u)) >> 16);
}

__device__ __forceinline__ float bf16_to_f32(unsigned short u) {
    unsigned v = ((unsigned)u) << 16;
    return __builtin_bit_cast(float, v);
}

// ---------------------------------------------------------------------------
// MFMA GEMM: out[t][n] = sum_k X[t][k] * W[n][k] + bias[n]
// Swapped operands: D = mfma(A=W, B=X) -> D col = token, row = channel.
// Block: 256 thr / 4 waves, 64 tokens; full W staged bf16 in LDS (pad 104).
// NCH=288 & !OUT_F32: channels split 96/96/96 into o0/o1/o2 (bf16).
// NCH=96 & OUT_F32: single fp32 output o0.
// ---------------------------------------------------------------------------
template <int NCH, bool IN_BF16, bool OUT_F32>
__global__ __launch_bounds__(256, 2) void gemm_mfma_kernel(
    const void* __restrict__ Xv, const float* __restrict__ W,
    const float* __restrict__ bias, void* __restrict__ o0,
    void* __restrict__ o1, void* __restrict__ o2)
{
    __shared__ unsigned short Ws[NCH * 104];
    __shared__ unsigned short Xs[64 * 104];
    const int tid = threadIdx.x;
    const int wid = tid >> 6, lane = tid & 63;
    const int lo16 = lane & 15, hi = lane >> 4;
    const size_t tok0 = (size_t)blockIdx.x * 64;

    // stage W (fp32 -> bf16), row-major [NCH][96] -> [NCH][104]
    for (int i = tid; i < NCH * 24; i += 256) {
        int r = i / 24, c4 = i % 24;
        float4 wv = reinterpret_cast<const float4*>(W)[i];
        uint2 p;
        p.x = pack_bf16(wv.x, wv.y);
        p.y = pack_bf16(wv.z, wv.w);
        *reinterpret_cast<uint2*>(&Ws[r * 104 + c4 * 4]) = p;
    }
    // stage X tile (64 tokens)
    if constexpr (IN_BF16) {
        const unsigned short* Xg = (const unsigned short*)Xv;
        for (int i = tid; i < 768; i += 256) {
            int t = i / 12, c8 = i % 12;
            int4 v = *reinterpret_cast<const int4*>(Xg + (tok0 + t) * 96 + c8 * 8);
            *reinterpret_cast<int4*>(&Xs[t * 104 + c8 * 8]) = v;
        }
    } else {
        const float* Xg = (const float*)Xv;
        for (int i = tid; i < 1536; i += 256) {
            int t = i / 24, c4 = i % 24;
            float4 v = *reinterpret_cast<const float4*>(Xg + (tok0 + t) * 96 + c4 * 4);
            uint2 p;
            p.x = pack_bf16(v.x, v.y);
            p.y = pack_bf16(v.z, v.w);
            *reinterpret_cast<uint2*>(&Xs[t * 104 + c4 * 4]) = p;
        }
    }
    __syncthreads();

    // B-fragments: this wave's token = wid*16 + lo16
    const int trow = wid * 16 + lo16;
    bf16x8 xb[3];
#pragma unroll
    for (int ks = 0; ks < 3; ++ks)
        xb[ks] = *reinterpret_cast<const bf16x8*>(&Xs[trow * 104 + ks * 32 + hi * 8]);

    constexpr int NT = NCH / 16;
    f32x4 acc[NT];
#pragma unroll
    for (int ct = 0; ct < NT; ++ct) acc[ct] = (f32x4){0.f, 0.f, 0.f, 0.f};
#pragma unroll
    for (int ct = 0; ct < NT; ++ct) {
#pragma unroll
        for (int ks = 0; ks < 3; ++ks) {
            bf16x8 af = *reinterpret_cast<const bf16x8*>(
                &Ws[(ct * 16 + lo16) * 104 + ks * 32 + hi * 8]);
            acc[ct] = __builtin_amdgcn_mfma_f32_16x16x32_bf16(af, xb[ks], acc[ct], 0, 0, 0);
        }
    }

    // epilogue: lane holds channels ct*16 + hi*4 .. +3 for token `tok`
    const size_t tok = tok0 + trow;
#pragma unroll
    for (int ct = 0; ct < NT; ++ct) {
        int ch = ct * 16 + hi * 4;
        float4 bv = *reinterpret_cast<const float4*>(bias + ch);
        float r0 = acc[ct][0] + bv.x, r1 = acc[ct][1] + bv.y;
        float r2 = acc[ct][2] + bv.z, r3 = acc[ct][3] + bv.w;
        if constexpr (OUT_F32) {
            *reinterpret_cast<float4*>((float*)o0 + tok * 96 + ch) =
                make_float4(r0, r1, r2, r3);
        } else {
            unsigned short* ob =
                (unsigned short*)((ct < 6) ? o0 : (ct < 12 ? o1 : o2));
            int lch = (ct % 6) * 16 + hi * 4;
            uint2 p;
            p.x = pack_bf16(r0, r1);
            p.y = pack_bf16(r2, r3);
            *reinterpret_cast<uint2*>(ob + tok * 96 + lch) = p;
        }
    }
}

// ---------------------------------------------------------------------------
// Depthwise 3x3 conv (pad 1, stride) + LayerNorm over C=96. bf16 in/out.
// TRANSPOSED=false: out [B][Lp][96]; TRANSPOSED=true: out [B][96][Lp].
// ---------------------------------------------------------------------------
template <bool TRANSPOSED>
__global__ __launch_bounds__(96) void pool_ln_kernel(
    const unsigned short* __restrict__ in, const float* __restrict__ wconv,
    const float* __restrict__ g, const float* __restrict__ beta,
    unsigned short* __restrict__ out, int stride, int Hp, int Wp)
{
    const int c = threadIdx.x;           // 0..95
    const int xo = blockIdx.x;
    const int yo = blockIdx.y;
    const int b  = blockIdx.z;

    float wv[9];
#pragma unroll
    for (int t = 0; t < 9; ++t) wv[t] = wconv[c * 9 + t];

    float v = 0.f;
#pragma unroll
    for (int ky = 0; ky < 3; ++ky) {
        int iy = yo * stride + ky - 1;
        if ((unsigned)iy < (unsigned)H_IN) {
#pragma unroll
            for (int kx = 0; kx < 3; ++kx) {
                int ix = xo * stride + kx - 1;
                if ((unsigned)ix < (unsigned)W_IN) {
                    v += wv[ky * 3 + kx] *
                         bf16_to_f32(in[(((size_t)b * H_IN + iy) * W_IN + ix) * 96 + c]);
                }
            }
        }
    }

    __shared__ float s1[96], s2[96];
    __shared__ float red[2];
    s1[c] = v;
    s2[c] = v * v;
    __syncthreads();
    if (c < 32) {
        float a = s1[c] + s1[c + 32] + s1[c + 64];
        float q = s2[c] + s2[c + 32] + s2[c + 64];
#pragma unroll
        for (int off = 16; off >= 1; off >>= 1) {
            a += __shfl_down(a, off, 32);
            q += __shfl_down(q, off, 32);
        }
        if (c == 0) { red[0] = a; red[1] = q; }
    }
    __syncthreads();
    float mu = red[0] * (1.f / 96.f);
    float var = red[1] * (1.f / 96.f) - mu * mu;
    float rstd = rsqrtf(var + 1e-6f);
    float r = (v - mu) * rstd * g[c] + beta[c];

    const int tok = yo * Wp + xo;
    const int Lp = Hp * Wp;
    if (TRANSPOSED)
        out[((size_t)b * 96 + c) * Lp + tok] = cvt_bf16(r);
    else
        out[((size_t)b * Lp + tok) * 96 + c] = cvt_bf16(r);
}

// ---------------------------------------------------------------------------
// MFMA flash attention + residual (bf16 out).
// 256 threads = 4 waves; each wave owns 16 q rows (block: 64 q rows).
// ---------------------------------------------------------------------------
__global__ __launch_bounds__(256, 3) void attn_mfma_kernel(
    const unsigned short* __restrict__ qb, const unsigned short* __restrict__ kb,
    const unsigned short* __restrict__ vtb, unsigned short* __restrict__ out)
{
    __shared__ unsigned short Kl[KVB * KLDS_W];   // 23296 B
    __shared__ unsigned short Vt[96 * VLDS_W];    // 26112 B

    const int tid = threadIdx.x;
    const int wid = tid >> 6;
    const int lane = tid & 63;
    const int lo16 = lane & 15;
    const int hi = lane >> 4;          // 0..3
    const int b = blockIdx.y;
    const int qrow = blockIdx.x * 64 + wid * 16 + lo16;

    // zero-fill V^T pad columns 112..127 (partial PV k-step reads them)
    for (int i = tid; i < 192; i += 256) {
        int row = i >> 1, col = 112 + (i & 1) * 8;
        *reinterpret_cast<int4*>(&Vt[row * VLDS_W + col]) = make_int4(0, 0, 0, 0);
    }

    // Q fragments (B-operand of S^T mfma): Q[q=lo16][k = ks*32 + hi*8 + i]
    bf16x8 qfrag[3];
    const unsigned short* qr = qb + ((size_t)b * N_IN + qrow) * 96;
#pragma unroll
    for (int ks = 0; ks < 3; ++ks)
        qfrag[ks] = *reinterpret_cast<const bf16x8*>(qr + ks * 32 + hi * 8);

    f32x4 acc[6];
#pragma unroll
    for (int mt = 0; mt < 6; ++mt) acc[mt] = (f32x4){0.f, 0.f, 0.f, 0.f};
    float m = -INFINITY, l = 0.f;

    const float SC = 0.1020620726159658f * 1.4426950408889634f; // scale*log2e
    const unsigned short* kg0 = kb + (size_t)b * LKV * 96;
    const unsigned short* vg0 = vtb + (size_t)b * 96 * LKV;

    for (int t = 0; t < 7; ++t) {
        __syncthreads();
        // stage K tile [112][96] -> Kl (padded rows)
        const unsigned short* kg = kg0 + (size_t)t * KVB * 96;
        for (int i = tid; i < 1344; i += 256) {
            int r = i / 12, cc = i % 12;
            *reinterpret_cast<int4*>(&Kl[r * KLDS_W + cc * 8]) =
                *reinterpret_cast<const int4*>(kg + r * 96 + cc * 8);
        }
        // stage V^T tile [96][112] -> Vt (padded rows)
        const unsigned short* vg = vg0 + t * KVB;
        for (int i = tid; i < 1344; i += 256) {
            int r = i / 14, cc = i % 14;
            *reinterpret_cast<int4*>(&Vt[r * VLDS_W + cc * 8]) =
                *reinterpret_cast<const int4*>(vg + (size_t)r * LKV + cc * 8);
        }
        __syncthreads();

        // S^T tiles: 7 x (16 kv x 16 q), each 3 mfma over k=96
        f32x4 st[7];
#pragma unroll
        for (int tt = 0; tt < 7; ++tt) {
            f32x4 s = (f32x4){0.f, 0.f, 0.f, 0.f};
#pragma unroll
            for (int ks = 0; ks < 3; ++ks) {
                bf16x8 af = *reinterpret_cast<const bf16x8*>(
                    &Kl[(tt * 16 + lo16) * KLDS_W + ks * 32 + hi * 8]);
                s = __builtin_amdgcn_mfma_f32_16x16x32_bf16(af, qfrag[ks], s, 0, 0, 0);
            }
#pragma unroll
            for (int r = 0; r < 4; ++r) s[r] *= SC;
            st[tt] = s;
        }

        // row max across kv (per q): in-lane then across hi via shfl_xor
        float tm = st[0][0];
#pragma unroll
        for (int tt = 0; tt < 7; ++tt)
#pragma unroll
            for (int r = 0; r < 4; ++r) tm = fmaxf(tm, st[tt][r]);
        tm = fmaxf(tm, __shfl_xor(tm, 16));
        tm = fmaxf(tm, __shfl_xor(tm, 32));

        float mnew = fmaxf(m, tm);
        float corr = exp2f(m - mnew);   // exp2f(-inf)=0 handles first tile
        m = mnew;
        l *= corr;
#pragma unroll
        for (int mt = 0; mt < 6; ++mt)
#pragma unroll
            for (int r = 0; r < 4; ++r) acc[mt][r] *= corr;

        // p = exp2(s - m); accumulate l; pack to bf16 pairs
        unsigned pk0[7], pk1[7];
        float ls = 0.f;
#pragma unroll
        for (int tt = 0; tt < 7; ++tt) {
            float p0 = exp2f(st[tt][0] - m);
            float p1 = exp2f(st[tt][1] - m);
            float p2 = exp2f(st[tt][2] - m);
            float p3 = exp2f(st[tt][3] - m);
            ls += (p0 + p1) + (p2 + p3);
            pk0[tt] = pack_bf16(p0, p1);
            pk1[tt] = pack_bf16(p2, p3);
        }
        l += ls;

        // PV: O^T += V^T * P^T   (4 k-steps of 32 kv; last is partial/padded)
        const int src0 = lo16 + ((hi & 1) ? 32 : 0);
        const int src1 = src0 + 16;
        const bool up = (hi & 2);
#pragma unroll
        for (int ks = 0; ks < 4; ++ks) {
            unsigned w0, w1, w2, w3;
            {
                unsigned a0 = __shfl(pk0[2 * ks], src0);
                unsigned a1 = __shfl(pk1[2 * ks], src0);
                unsigned a2 = __shfl(pk0[2 * ks], src1);
                unsigned a3 = __shfl(pk1[2 * ks], src1);
                if (ks < 3) {
                    unsigned b0 = __shfl(pk0[2 * ks + 1], src0);
                    unsigned b1 = __shfl(pk1[2 * ks + 1], src0);
                    unsigned b2 = __shfl(pk0[2 * ks + 1], src1);
                    unsigned b3 = __shfl(pk1[2 * ks + 1], src1);
                    w0 = up ? b0 : a0; w1 = up ? b1 : a1;
                    w2 = up ? b2 : a2; w3 = up ? b3 : a3;
                } else {
                    w0 = up ? 0u : a0; w1 = up ? 0u : a1;
                    w2 = up ? 0u : a2; w3 = up ? 0u : a3;
                }
            }
            int4 bw = make_int4((int)w0, (int)w1, (int)w2, (int)w3);
            bf16x8 bfrag = __builtin_bit_cast(bf16x8, bw);
#pragma unroll
            for (int mt = 0; mt < 6; ++mt) {
                bf16x8 af = *reinterpret_cast<const bf16x8*>(
                    &Vt[(mt * 16 + lo16) * VLDS_W + ks * 32 + hi * 8]);
                acc[mt] = __builtin_amdgcn_mfma_f32_16x16x32_bf16(af, bfrag, acc[mt], 0, 0, 0);
            }
        }
    }

    // final l reduce across the 4 lane-groups sharing this q
    l += __shfl_xor(l, 16);
    l += __shfl_xor(l, 32);
    const float inv = 1.f / l;

    // epilogue: out[q][ch] = acc/l + q_residual (bf16); ch = mt*16 + hi*4
    unsigned short* op = out + ((size_t)b * N_IN + qrow) * 96;
#pragma unroll
    for (int mt = 0; mt < 6; ++mt) {
        int ch = mt * 16 + hi * 4;
        ushort4 qres = *reinterpret_cast<const ushort4*>(qr + ch);
        uint2 p;
        p.x = pack_bf16(acc[mt][0] * inv + bf16_to_f32(qres.x),
                        acc[mt][1] * inv + bf16_to_f32(qres.y));
        p.y = pack_bf16(acc[mt][2] * inv + bf16_to_f32(qres.z),
                        acc[mt][3] * inv + bf16_to_f32(qres.w));
        *reinterpret_cast<uint2*>(op + ch) = p;
    }
}

// ---------------------------------------------------------------------------
extern "C" void kernel_launch(void* const* d_in, const int* in_sizes, int n_in,
                              void* d_out, int out_size, void* d_ws, size_t ws_size,
                              hipStream_t stream)
{
    const float* x     = (const float*)d_in[0];
    const float* Wqkv  = (const float*)d_in[1];
    const float* bqkv  = (const float*)d_in[2];
    const float* pqw   = (const float*)d_in[3];
    const float* gq    = (const float*)d_in[4];
    const float* betq  = (const float*)d_in[5];
    const float* pkw   = (const float*)d_in[6];
    const float* gk    = (const float*)d_in[7];
    const float* betk  = (const float*)d_in[8];
    const float* pvw   = (const float*)d_in[9];
    const float* gv    = (const float*)d_in[10];
    const float* betv  = (const float*)d_in[11];
    const float* Wproj = (const float*)d_in[12];
    const float* bproj = (const float*)d_in[13];
    float* outp = (float*)d_out;

    char* ws = (char*)d_ws;
    const size_t QB    = (size_t)BATCH * N_IN * 96 * sizeof(short);   // 19.27 MB
    const size_t KVBYT = (size_t)BATCH * LKV * 96 * sizeof(short);    // 4.8 MB
    unsigned short* qb   = (unsigned short*)(ws);
    unsigned short* kbuf = (unsigned short*)(ws + QB);
    unsigned short* vbuf = (unsigned short*)(ws + 2 * QB);
    unsigned short* qpb  = (unsigned short*)(ws + 3 * QB);
    unsigned short* kpb  = (unsigned short*)(ws + 4 * QB);
    unsigned short* vptb = (unsigned short*)(ws + 4 * QB + KVBYT);
    unsigned short* attn_out = qb;   // qb dead after pool_q

    const int T = BATCH * N_IN;      // 100352 tokens

    // 1. QKV projection (MFMA) -> q,k,v bf16 [B][3136][96]
    gemm_mfma_kernel<288, false, false><<<T / 64, 256, 0, stream>>>(
        x, Wqkv, bqkv, qb, kbuf, vbuf);
    // 2-4. depthwise conv + LN pools -> bf16 (v transposed)
    pool_ln_kernel<false><<<dim3(56, 56, BATCH), 96, 0, stream>>>(qb, pqw, gq, betq, qpb, 1, 56, 56);
    pool_ln_kernel<false><<<dim3(28, 28, BATCH), 96, 0, stream>>>(kbuf, pkw, gk, betk, kpb, 2, 28, 28);
    pool_ln_kernel<true ><<<dim3(28, 28, BATCH), 96, 0, stream>>>(vbuf, pvw, gv, betv, vptb, 2, 28, 28);
    // 5. MFMA attention + residual (bf16 out)
    attn_mfma_kernel<<<dim3(N_IN / 64, BATCH), 256, 0, stream>>>(qpb, kpb, vptb, attn_out);
    // 6. output projection (MFMA, fp32 out)
    gemm_mfma_kernel<96, true, true><<<T / 64, 256, 0, stream>>>(
        attn_out, Wproj, bproj, outp, nullptr, nullptr);
}

// Round 4
// 268.083 us; speedup vs baseline: 9.4726x; 1.2506x over previous
//
#include <hip/hip_runtime.h>
#include <hip/hip_bf16.h>
#include <cmath>

#define BATCH 32
#define H_IN 56
#define W_IN 56
#define N_IN (H_IN * W_IN)   // 3136
#define LKV 784              // 28*28 pooled kv length

typedef short bf16x8 __attribute__((ext_vector_type(8)));
typedef float f32x4 __attribute__((ext_vector_type(4)));
typedef float f32x16 __attribute__((ext_vector_type(16)));

__device__ __forceinline__ unsigned pack_bf16(float a, float b) {
    unsigned ua = __builtin_bit_cast(unsigned, a);
    unsigned ub = __builtin_bit_cast(unsigned, b);
    ua = (ua + 0x7FFFu + ((ua >> 16) & 1u)) >> 16;
    ub = (ub + 0x7FFFu + ((ub >> 16) & 1u)) >> 16;
    return ua | (ub << 16);
}

__device__ __forceinline__ unsigned short cvt_bf16(float a) {
    unsigned ua = __builtin_bit_cast(unsigned, a);
    return (unsigned short)((ua + 0x7FFFu + ((ua >> 16) & 1u)) >> 16);
}

__device__ __forceinline__ float bf16_to_f32(unsigned short u) {
    unsigned v = ((unsigned)u) << 16;
    return __builtin_bit_cast(float, v);
}

// [lo16 = trunc-bf16(a), hi16 = trunc-bf16(b)] in one v_perm
__device__ __forceinline__ unsigned pack_trunc(float a, float b) {
    return __builtin_amdgcn_perm(__builtin_bit_cast(unsigned, b),
                                 __builtin_bit_cast(unsigned, a), 0x07060302u);
}

__device__ __forceinline__ f32x16 zero16() {
    f32x16 z;
#pragma unroll
    for (int i = 0; i < 16; ++i) z[i] = 0.f;
    return z;
}

// ---------------------------------------------------------------------------
// One-time W prep: fp32 row-major [NCH][96] -> bf16 A-fragment order.
// Frag(ct,kb): lane holds ch=ct*16+(lane&15), k=kb*32+(lane>>4)*8 .. +7.
// Wqkv: 18 ct * 3 kb = 54 frags (3456 pieces); Wproj: 6 ct -> 1152 pieces.
// ---------------------------------------------------------------------------
__global__ __launch_bounds__(256) void wprep_kernel(
    const float* __restrict__ Wqkv, const float* __restrict__ Wproj,
    unsigned short* __restrict__ wq, unsigned short* __restrict__ wp)
{
    int idx = blockIdx.x * 256 + threadIdx.x;   // 0..4607
    const float* src; unsigned short* dst; int li;
    if (idx < 3456) { src = Wqkv; dst = wq; li = idx; }
    else            { src = Wproj; dst = wp; li = idx - 3456; }
    int frag = li >> 6, ln = li & 63;
    int ct = frag / 3, kkb = frag % 3;
    int ch = ct * 16 + (ln & 15);
    int k0 = kkb * 32 + (ln >> 4) * 8;
    const float* s = src + ch * 96 + k0;
    float4 v0 = *reinterpret_cast<const float4*>(s);
    float4 v1 = *reinterpret_cast<const float4*>(s + 4);
    uint4 o;
    o.x = pack_bf16(v0.x, v0.y); o.y = pack_bf16(v0.z, v0.w);
    o.z = pack_bf16(v1.x, v1.y); o.w = pack_bf16(v1.z, v1.w);
    *reinterpret_cast<uint4*>(dst + (size_t)li * 8) = o;
}

// ---------------------------------------------------------------------------
// MFMA GEMM v2: out[t][n] = sum_k X[t][k]*W[n][k] + bias[n]
// 256 thr / 4 waves; 256 tokens per block (64/wave = 4 iters x 16).
// W staged from pre-converted frag-order bf16 (lane-linear, conflict-free);
// X fragments loaded straight from global into registers (read exactly once).
// ---------------------------------------------------------------------------
template <int NCT, bool IN_BF16, bool OUT_F32>
__global__ __launch_bounds__(256, 2) void gemm2_kernel(
    const void* __restrict__ Xv, const unsigned short* __restrict__ Wfr,
    const float* __restrict__ bias, void* __restrict__ o0,
    void* __restrict__ o1, void* __restrict__ o2)
{
    __shared__ unsigned short Wl[NCT * 192 * 8];
    const int tid = threadIdx.x;
    const int wid = tid >> 6, lane = tid & 63;
    const int lo16 = lane & 15, hi = lane >> 4;

    for (int idx = tid; idx < NCT * 192; idx += 256)
        *reinterpret_cast<int4*>(&Wl[idx * 8]) =
            *reinterpret_cast<const int4*>(Wfr + (size_t)idx * 8);

    const size_t tok0 = (size_t)blockIdx.x * 256 + wid * 64;
    bf16x8 xb[12];
#pragma unroll
    for (int it = 0; it < 4; ++it) {
        size_t t = tok0 + it * 16 + lo16;
#pragma unroll
        for (int kkb = 0; kkb < 3; ++kkb) {
            if constexpr (IN_BF16) {
                xb[it * 3 + kkb] = *reinterpret_cast<const bf16x8*>(
                    (const unsigned short*)Xv + t * 96 + kkb * 32 + hi * 8);
            } else {
                const float* xp = (const float*)Xv + t * 96 + kkb * 32 + hi * 8;
                float4 a = *reinterpret_cast<const float4*>(xp);
                float4 c = *reinterpret_cast<const float4*>(xp + 4);
                uint4 u;
                u.x = pack_bf16(a.x, a.y); u.y = pack_bf16(a.z, a.w);
                u.z = pack_bf16(c.x, c.y); u.w = pack_bf16(c.z, c.w);
                xb[it * 3 + kkb] = __builtin_bit_cast(bf16x8, u);
            }
        }
    }
    __syncthreads();

#pragma unroll
    for (int ct = 0; ct < NCT; ++ct) {
        bf16x8 wf[3];
#pragma unroll
        for (int kkb = 0; kkb < 3; ++kkb)
            wf[kkb] = *reinterpret_cast<const bf16x8*>(&Wl[((ct * 3 + kkb) * 64 + lane) * 8]);
        const int chb = ct * 16 + hi * 4;
        float4 bv = *reinterpret_cast<const float4*>(bias + chb);
#pragma unroll
        for (int it = 0; it < 4; ++it) {
            f32x4 a = (f32x4){0.f, 0.f, 0.f, 0.f};
#pragma unroll
            for (int kkb = 0; kkb < 3; ++kkb)
                a = __builtin_amdgcn_mfma_f32_16x16x32_bf16(wf[kkb], xb[it * 3 + kkb], a, 0, 0, 0);
            size_t t = tok0 + it * 16 + lo16;
            float r0 = a[0] + bv.x, r1 = a[1] + bv.y;
            float r2 = a[2] + bv.z, r3 = a[3] + bv.w;
            if constexpr (OUT_F32) {
                *reinterpret_cast<float4*>((float*)o0 + t * 96 + chb) =
                    make_float4(r0, r1, r2, r3);
            } else {
                unsigned short* ob =
                    (unsigned short*)((ct < 6) ? o0 : (ct < 12 ? o1 : o2));
                int lch = (ct % 6) * 16 + hi * 4;
                uint2 p;
                p.x = pack_bf16(r0, r1);
                p.y = pack_bf16(r2, r3);
                *reinterpret_cast<uint2*>(ob + t * 96 + lch) = p;
            }
        }
    }
}

// ---------------------------------------------------------------------------
// Depthwise 3x3 conv (pad 1, stride) + LayerNorm over C=96, bf16 in/out.
// oscale folds attention scale*log2e into K. TRANSPOSED: out [B][96][Lp].
// ---------------------------------------------------------------------------
template <bool TRANSPOSED>
__global__ __launch_bounds__(96) void pool_ln_kernel(
    const unsigned short* __restrict__ in, const float* __restrict__ wconv,
    const float* __restrict__ g, const float* __restrict__ beta,
    unsigned short* __restrict__ out, int stride, int Hp, int Wp, float oscale)
{
    const int c = threadIdx.x;           // 0..95
    const int xo = blockIdx.x;
    const int yo = blockIdx.y;
    const int b  = blockIdx.z;

    float wv[9];
#pragma unroll
    for (int t = 0; t < 9; ++t) wv[t] = wconv[c * 9 + t];

    float v = 0.f;
#pragma unroll
    for (int ky = 0; ky < 3; ++ky) {
        int iy = yo * stride + ky - 1;
        if ((unsigned)iy < (unsigned)H_IN) {
#pragma unroll
            for (int kx = 0; kx < 3; ++kx) {
                int ix = xo * stride + kx - 1;
                if ((unsigned)ix < (unsigned)W_IN) {
                    v += wv[ky * 3 + kx] *
                         bf16_to_f32(in[(((size_t)b * H_IN + iy) * W_IN + ix) * 96 + c]);
                }
            }
        }
    }

    __shared__ float s1[96], s2[96];
    __shared__ float red[2];
    s1[c] = v;
    s2[c] = v * v;
    __syncthreads();
    if (c < 32) {
        float a = s1[c] + s1[c + 32] + s1[c + 64];
        float q = s2[c] + s2[c + 32] + s2[c + 64];
#pragma unroll
        for (int off = 16; off >= 1; off >>= 1) {
            a += __shfl_down(a, off, 32);
            q += __shfl_down(q, off, 32);
        }
        if (c == 0) { red[0] = a; red[1] = q; }
    }
    __syncthreads();
    float mu = red[0] * (1.f / 96.f);
    float var = red[1] * (1.f / 96.f) - mu * mu;
    float rstd = rsqrtf(var + 1e-6f);
    float r = ((v - mu) * rstd * g[c] + beta[c]) * oscale;

    const int tok = yo * Wp + xo;
    const int Lp = Hp * Wp;
    if (TRANSPOSED)
        out[((size_t)b * 96 + c) * Lp + tok] = cvt_bf16(r);
    else
        out[((size_t)b * Lp + tok) * 96 + c] = cvt_bf16(r);
}

// ---------------------------------------------------------------------------
// MFMA flash attention v2 + residual (bf16 out).
// 32x32x16 MFMA, 4 waves x 32 q = 128 q rows/block. Fixed-m softmax
// (scale*log2e folded into K; LN-bounded scores => exp2 cannot overflow).
// K and V^T staged in FRAGMENT ORDER (lane-linear 16B) -> no bank conflicts.
// KV padded 784->864 (9 chunks of 96): pad K rows staged as 0 (p=1 excluded
// from l by mask), pad V rows 0 (no PV contribution); chunk 8 computes only
// its valid tile / kv-block.
// ---------------------------------------------------------------------------
__global__ __launch_bounds__(256, 3) void attn_mfma2_kernel(
    const unsigned short* __restrict__ qpl, const unsigned short* __restrict__ kpl,
    const unsigned short* __restrict__ vtp, unsigned short* __restrict__ out)
{
    __shared__ unsigned short Kl[18 * 64 * 8];   // 18 KB, frag-order
    __shared__ unsigned short Vl[18 * 64 * 8];   // 18 KB, frag-order

    const int tid = threadIdx.x;
    const int wid = tid >> 6, lane = tid & 63;
    const int l31 = lane & 31, h = lane >> 5;
    const int b = blockIdx.y;
    const int qrow = blockIdx.x * 128 + wid * 32 + l31;
    const int qrl = qrow < N_IN ? qrow : N_IN - 1;

    // Q fragments (B-operand): lane holds q=l31, k = kb*16 + h*8 + i
    const unsigned short* qptr = qpl + ((size_t)b * N_IN + qrl) * 96;
    bf16x8 qf[6];
#pragma unroll
    for (int kkb = 0; kkb < 6; ++kkb)
        qf[kkb] = *reinterpret_cast<const bf16x8*>(qptr + kkb * 16 + h * 8);

    f32x16 acc0 = zero16(), acc1 = zero16(), acc2 = zero16();
    float lsum = 0.f;

    const unsigned short* kg0 = kpl + (size_t)b * LKV * 96;
    const unsigned short* vg0 = vtp + (size_t)b * 96 * LKV;

    for (int ck = 0; ck < 9; ++ck) {
        const int base = ck * 96;
        __syncthreads();
        // stage K chunk: frag(tt,kb): lane ln -> K[base+tt*32+(ln&31)][kb*16+(ln>>5)*8 ..+7]
        for (int idx = tid; idx < 1152; idx += 256) {
            int frag = idx >> 6, ln = idx & 63;
            int tt = frag / 6, kkb = frag % 6;
            int kv = base + tt * 32 + (ln & 31);
            int k0 = kkb * 16 + (ln >> 5) * 8;
            int4 v = make_int4(0, 0, 0, 0);
            if (kv < LKV) v = *reinterpret_cast<const int4*>(kg0 + (size_t)kv * 96 + k0);
            *reinterpret_cast<int4*>(&Kl[idx * 8]) = v;
        }
        // stage V^T chunk: frag(ct,kb2): lane ln -> VT[ct*32+(ln&31)][base+kb2*16+(ln>>5)*8 ..+7]
        for (int idx = tid; idx < 1152; idx += 256) {
            int frag = idx >> 6, ln = idx & 63;
            int ct = frag / 6, kb2 = frag % 6;
            int chn = ct * 32 + (ln & 31);
            int kv0 = base + kb2 * 16 + (ln >> 5) * 8;
            int4 v = make_int4(0, 0, 0, 0);
            if (kv0 < LKV) v = *reinterpret_cast<const int4*>(vg0 + (size_t)chn * LKV + kv0);
            *reinterpret_cast<int4*>(&Vl[idx * 8]) = v;
        }
        __syncthreads();

        const int ntl = (ck == 8) ? 1 : 3;
        for (int tt = 0; tt < ntl; ++tt) {
            int nval = LKV - base - tt * 32;
            if (nval > 32) nval = 32;

            // S^T tile (32 kv x 32 q): 6 mfma over k=96
            f32x16 s = zero16();
#pragma unroll
            for (int kkb = 0; kkb < 6; ++kkb) {
                bf16x8 af = *reinterpret_cast<const bf16x8*>(
                    &Kl[((tt * 6 + kkb) * 64 + lane) * 8]);
                s = __builtin_amdgcn_mfma_f32_32x32x16_bf16(af, qf[kkb], s, 0, 0, 0);
            }

            // p = exp2(s), truncated to bf16 (l sums the truncated values)
            float p[16];
#pragma unroll
            for (int r = 0; r < 16; ++r) {
                float e = exp2f(s[r]);
                unsigned u = __builtin_bit_cast(unsigned, e) & 0xFFFF0000u;
                p[r] = __builtin_bit_cast(float, u);
            }
            if (nval == 32) {
                float a0 = 0.f, a1 = 0.f;
#pragma unroll
                for (int r = 0; r < 8; ++r) { a0 += p[r]; a1 += p[r + 8]; }
                lsum += a0 + a1;
            } else {
                float a0 = 0.f;
#pragma unroll
                for (int r = 0; r < 8; ++r) a0 += p[r];
                lsum += a0;
            }

            // pack P^T pairs and exchange halves (lane ^ 32)
            unsigned d[8], sw[8];
#pragma unroll
            for (int j = 0; j < 8; ++j) d[j] = pack_trunc(p[2 * j], p[2 * j + 1]);
#pragma unroll
            for (int j = 0; j < 8; ++j) sw[j] = (unsigned)__shfl_xor((int)d[j], 32);

            // PV kv-block 0 (kv tt*32 + 0..15)
            {
                int4 bi = h ? make_int4((int)sw[2], (int)sw[3], (int)d[2], (int)d[3])
                            : make_int4((int)d[0], (int)d[1], (int)sw[0], (int)sw[1]);
                bf16x8 bf = __builtin_bit_cast(bf16x8, bi);
                int vf = tt * 2;
                bf16x8 a0 = *reinterpret_cast<const bf16x8*>(&Vl[((0 * 6 + vf) * 64 + lane) * 8]);
                bf16x8 a1 = *reinterpret_cast<const bf16x8*>(&Vl[((1 * 6 + vf) * 64 + lane) * 8]);
                bf16x8 a2 = *reinterpret_cast<const bf16x8*>(&Vl[((2 * 6 + vf) * 64 + lane) * 8]);
                acc0 = __builtin_amdgcn_mfma_f32_32x32x16_bf16(a0, bf, acc0, 0, 0, 0);
                acc1 = __builtin_amdgcn_mfma_f32_32x32x16_bf16(a1, bf, acc1, 0, 0, 0);
                acc2 = __builtin_amdgcn_mfma_f32_32x32x16_bf16(a2, bf, acc2, 0, 0, 0);
            }
            // PV kv-block 1 (kv tt*32 + 16..31), skipped in the padded tail
            if (nval == 32) {
                int4 bi = h ? make_int4((int)sw[6], (int)sw[7], (int)d[6], (int)d[7])
                            : make_int4((int)d[4], (int)d[5], (int)sw[4], (int)sw[5]);
                bf16x8 bf = __builtin_bit_cast(bf16x8, bi);
                int vf = tt * 2 + 1;
                bf16x8 a0 = *reinterpret_cast<const bf16x8*>(&Vl[((0 * 6 + vf) * 64 + lane) * 8]);
                bf16x8 a1 = *reinterpret_cast<const bf16x8*>(&Vl[((1 * 6 + vf) * 64 + lane) * 8]);
                bf16x8 a2 = *reinterpret_cast<const bf16x8*>(&Vl[((2 * 6 + vf) * 64 + lane) * 8]);
                acc0 = __builtin_amdgcn_mfma_f32_32x32x16_bf16(a0, bf, acc0, 0, 0, 0);
                acc1 = __builtin_amdgcn_mfma_f32_32x32x16_bf16(a1, bf, acc1, 0, 0, 0);
                acc2 = __builtin_amdgcn_mfma_f32_32x32x16_bf16(a2, bf, acc2, 0, 0, 0);
            }
        }
    }

    // l: other 16 kv of each tile live in lane^32
    lsum += __shfl_xor(lsum, 32);
    const float inv = 1.f / lsum;

    if (qrow < N_IN) {
        const unsigned short* qres = qpl + ((size_t)b * N_IN + qrow) * 96;
        unsigned short* op = out + ((size_t)b * N_IN + qrow) * 96;
#pragma unroll
        for (int ct = 0; ct < 3; ++ct) {
            const f32x16& a = (ct == 0) ? acc0 : (ct == 1 ? acc1 : acc2);
#pragma unroll
            for (int g = 0; g < 4; ++g) {
                int ch = ct * 32 + g * 8 + 4 * h;   // reg r=g*4+j -> ch offset g*8+4h+j
                ushort4 q4 = *reinterpret_cast<const ushort4*>(qres + ch);
                uint2 pr;
                pr.x = pack_bf16(a[g * 4 + 0] * inv + bf16_to_f32(q4.x),
                                 a[g * 4 + 1] * inv + bf16_to_f32(q4.y));
                pr.y = pack_bf16(a[g * 4 + 2] * inv + bf16_to_f32(q4.z),
                                 a[g * 4 + 3] * inv + bf16_to_f32(q4.w));
                *reinterpret_cast<uint2*>(op + ch) = pr;
            }
        }
    }
}

// ---------------------------------------------------------------------------
extern "C" void kernel_launch(void* const* d_in, const int* in_sizes, int n_in,
                              void* d_out, int out_size, void* d_ws, size_t ws_size,
                              hipStream_t stream)
{
    const float* x     = (const float*)d_in[0];
    const float* Wqkv  = (const float*)d_in[1];
    const float* bqkv  = (const float*)d_in[2];
    const float* pqw   = (const float*)d_in[3];
    const float* gq    = (const float*)d_in[4];
    const float* betq  = (const float*)d_in[5];
    const float* pkw   = (const float*)d_in[6];
    const float* gk    = (const float*)d_in[7];
    const float* betk  = (const float*)d_in[8];
    const float* pvw   = (const float*)d_in[9];
    const float* gv    = (const float*)d_in[10];
    const float* betv  = (const float*)d_in[11];
    const float* Wproj = (const float*)d_in[12];
    const float* bproj = (const float*)d_in[13];
    float* outp = (float*)d_out;

    char* ws = (char*)d_ws;
    const size_t QB    = (size_t)BATCH * N_IN * 96 * sizeof(short);   // 19.27 MB
    const size_t KVBYT = (size_t)BATCH * LKV * 96 * sizeof(short);    // 4.8 MB
    unsigned short* qb   = (unsigned short*)(ws);
    unsigned short* kbuf = (unsigned short*)(ws + QB);
    unsigned short* vbuf = (unsigned short*)(ws + 2 * QB);
    unsigned short* qpb  = (unsigned short*)(ws + 3 * QB);
    unsigned short* kpb  = (unsigned short*)(ws + 4 * QB);
    unsigned short* vptb = (unsigned short*)(ws + 4 * QB + KVBYT);
    unsigned short* wqf  = (unsigned short*)(ws + 4 * QB + 2 * KVBYT);
    unsigned short* wpf  = (unsigned short*)(ws + 4 * QB + 2 * KVBYT + 56320);
    unsigned short* attn_out = qb;   // qb dead after pool_q

    const int T = BATCH * N_IN;      // 100352 = 256 * 392

    const float SC = 0.1020620726159658f * 1.4426950408889634f; // scale*log2e

    // 0. one-time W -> bf16 frag-order
    wprep_kernel<<<18, 256, 0, stream>>>(Wqkv, Wproj, wqf, wpf);
    // 1. QKV projection (MFMA) -> q,k,v bf16 [B][3136][96]
    gemm2_kernel<18, false, false><<<T / 256, 256, 0, stream>>>(
        x, wqf, bqkv, qb, kbuf, vbuf);
    // 2-4. depthwise conv + LN pools -> bf16 (K scaled by SC, V transposed)
    pool_ln_kernel<false><<<dim3(56, 56, BATCH), 96, 0, stream>>>(qb, pqw, gq, betq, qpb, 1, 56, 56, 1.0f);
    pool_ln_kernel<false><<<dim3(28, 28, BATCH), 96, 0, stream>>>(kbuf, pkw, gk, betk, kpb, 2, 28, 28, SC);
    pool_ln_kernel<true ><<<dim3(28, 28, BATCH), 96, 0, stream>>>(vbuf, pvw, gv, betv, vptb, 2, 28, 28, 1.0f);
    // 5. MFMA attention v2 + residual (bf16 out)
    attn_mfma2_kernel<<<dim3(25, BATCH), 256, 0, stream>>>(qpb, kpb, vptb, attn_out);
    // 6. output projection (MFMA, fp32 out)
    gemm2_kernel<6, true, true><<<T / 256, 256, 0, stream>>>(
        attn_out, wpf, bproj, outp, nullptr, nullptr);
}

// Round 5
// 173.679 us; speedup vs baseline: 14.6215x; 1.5436x over previous
//
#include <hip/hip_runtime.h>
#include <hip/hip_bf16.h>
#include <cmath>

#define BATCH 32
#define H_IN 56
#define W_IN 56
#define N_IN (H_IN * W_IN)   // 3136
#define LKV 784              // 28*28 pooled kv length

typedef short bf16x8 __attribute__((ext_vector_type(8)));
typedef float f32x4 __attribute__((ext_vector_type(4)));
typedef float f32x16 __attribute__((ext_vector_type(16)));

__device__ __forceinline__ unsigned pack_bf16(float a, float b) {
    unsigned ua = __builtin_bit_cast(unsigned, a);
    unsigned ub = __builtin_bit_cast(unsigned, b);
    ua = (ua + 0x7FFFu + ((ua >> 16) & 1u)) >> 16;
    ub = (ub + 0x7FFFu + ((ub >> 16) & 1u)) >> 16;
    return ua | (ub << 16);
}

__device__ __forceinline__ unsigned short cvt_bf16(float a) {
    unsigned ua = __builtin_bit_cast(unsigned, a);
    return (unsigned short)((ua + 0x7FFFu + ((ua >> 16) & 1u)) >> 16);
}

__device__ __forceinline__ float bf16_to_f32(unsigned short u) {
    unsigned v = ((unsigned)u) << 16;
    return __builtin_bit_cast(float, v);
}

__device__ __forceinline__ float bflo(unsigned u) {
    return __builtin_bit_cast(float, u << 16);
}
__device__ __forceinline__ float bfhi(unsigned u) {
    return __builtin_bit_cast(float, u & 0xFFFF0000u);
}

// [lo16 = trunc-bf16(a), hi16 = trunc-bf16(b)] in one v_perm
__device__ __forceinline__ unsigned pack_trunc(float a, float b) {
    return __builtin_amdgcn_perm(__builtin_bit_cast(unsigned, b),
                                 __builtin_bit_cast(unsigned, a), 0x07060302u);
}

__device__ __forceinline__ f32x16 zero16() {
    f32x16 z;
#pragma unroll
    for (int i = 0; i < 16; ++i) z[i] = 0.f;
    return z;
}

// ---------------------------------------------------------------------------
// One-time weight prep:
//  idx <  3456 : Wqkv fp32 [288][96] -> bf16 A-frag order (54 frags)
//  idx <  4608 : Wproj fp32 [96][96] -> bf16 A-frag order (18 frags)
//  idx <  7200 : pool conv weights [96][9] -> transposed fp32 [3][9][96]
// ---------------------------------------------------------------------------
__global__ __launch_bounds__(256) void wprep_kernel(
    const float* __restrict__ Wqkv, const float* __restrict__ Wproj,
    const float* __restrict__ pqw, const float* __restrict__ pkw,
    const float* __restrict__ pvw,
    unsigned short* __restrict__ wq, unsigned short* __restrict__ wp,
    float* __restrict__ wpool)
{
    int idx = blockIdx.x * 256 + threadIdx.x;
    if (idx < 4608) {
        const float* src; unsigned short* dst; int li;
        if (idx < 3456) { src = Wqkv; dst = wq; li = idx; }
        else            { src = Wproj; dst = wp; li = idx - 3456; }
        int frag = li >> 6, ln = li & 63;
        int ct = frag / 3, kkb = frag % 3;
        int ch = ct * 16 + (ln & 15);
        int k0 = kkb * 32 + (ln >> 4) * 8;
        const float* s = src + ch * 96 + k0;
        float4 v0 = *reinterpret_cast<const float4*>(s);
        float4 v1 = *reinterpret_cast<const float4*>(s + 4);
        uint4 o;
        o.x = pack_bf16(v0.x, v0.y); o.y = pack_bf16(v0.z, v0.w);
        o.z = pack_bf16(v1.x, v1.y); o.w = pack_bf16(v1.z, v1.w);
        *reinterpret_cast<uint4*>(dst + (size_t)li * 8) = o;
    } else if (idx < 7200) {
        int li = idx - 4608;               // 0..2591
        int which = li / 864, r = li % 864;
        int tap = r / 96, c = r % 96;
        const float* src = (which == 0) ? pqw : (which == 1 ? pkw : pvw);
        wpool[which * 864 + tap * 96 + c] = src[c * 9 + tap];
    }
}

// ---------------------------------------------------------------------------
// MFMA GEMM v2: out[t][n] = sum_k X[t][k]*W[n][k] + bias[n]
// 256 thr / 4 waves; 256 tokens per block (64/wave = 4 iters x 16).
// ---------------------------------------------------------------------------
template <int NCT, bool IN_BF16, bool OUT_F32>
__global__ __launch_bounds__(256, 2) void gemm2_kernel(
    const void* __restrict__ Xv, const unsigned short* __restrict__ Wfr,
    const float* __restrict__ bias, void* __restrict__ o0,
    void* __restrict__ o1, void* __restrict__ o2)
{
    __shared__ unsigned short Wl[NCT * 192 * 8];
    const int tid = threadIdx.x;
    const int wid = tid >> 6, lane = tid & 63;
    const int lo16 = lane & 15, hi = lane >> 4;

    for (int idx = tid; idx < NCT * 192; idx += 256)
        *reinterpret_cast<int4*>(&Wl[idx * 8]) =
            *reinterpret_cast<const int4*>(Wfr + (size_t)idx * 8);

    const size_t tok0 = (size_t)blockIdx.x * 256 + wid * 64;
    bf16x8 xb[12];
#pragma unroll
    for (int it = 0; it < 4; ++it) {
        size_t t = tok0 + it * 16 + lo16;
#pragma unroll
        for (int kkb = 0; kkb < 3; ++kkb) {
            if constexpr (IN_BF16) {
                xb[it * 3 + kkb] = *reinterpret_cast<const bf16x8*>(
                    (const unsigned short*)Xv + t * 96 + kkb * 32 + hi * 8);
            } else {
                const float* xp = (const float*)Xv + t * 96 + kkb * 32 + hi * 8;
                float4 a = *reinterpret_cast<const float4*>(xp);
                float4 c = *reinterpret_cast<const float4*>(xp + 4);
                uint4 u;
                u.x = pack_bf16(a.x, a.y); u.y = pack_bf16(a.z, a.w);
                u.z = pack_bf16(c.x, c.y); u.w = pack_bf16(c.z, c.w);
                xb[it * 3 + kkb] = __builtin_bit_cast(bf16x8, u);
            }
        }
    }
    __syncthreads();

#pragma unroll
    for (int ct = 0; ct < NCT; ++ct) {
        bf16x8 wf[3];
#pragma unroll
        for (int kkb = 0; kkb < 3; ++kkb)
            wf[kkb] = *reinterpret_cast<const bf16x8*>(&Wl[((ct * 3 + kkb) * 64 + lane) * 8]);
        const int chb = ct * 16 + hi * 4;
        float4 bv = *reinterpret_cast<const float4*>(bias + chb);
#pragma unroll
        for (int it = 0; it < 4; ++it) {
            f32x4 a = (f32x4){0.f, 0.f, 0.f, 0.f};
#pragma unroll
            for (int kkb = 0; kkb < 3; ++kkb)
                a = __builtin_amdgcn_mfma_f32_16x16x32_bf16(wf[kkb], xb[it * 3 + kkb], a, 0, 0, 0);
            size_t t = tok0 + it * 16 + lo16;
            float r0 = a[0] + bv.x, r1 = a[1] + bv.y;
            float r2 = a[2] + bv.z, r3 = a[3] + bv.w;
            if constexpr (OUT_F32) {
                *reinterpret_cast<float4*>((float*)o0 + t * 96 + chb) =
                    make_float4(r0, r1, r2, r3);
            } else {
                unsigned short* ob =
                    (unsigned short*)((ct < 6) ? o0 : (ct < 12 ? o1 : o2));
                int lch = (ct % 6) * 16 + hi * 4;
                uint2 p;
                p.x = pack_bf16(r0, r1);
                p.y = pack_bf16(r2, r3);
                *reinterpret_cast<uint2*>(ob + t * 96 + lch) = p;
            }
        }
    }
}

// ---------------------------------------------------------------------------
// Pool v3: depthwise 3x3 conv (pad 1) + LayerNorm, bf16 in/out.
// Block = 192 threads = 16 tokens x 12 chunk-threads; each thread owns 8
// channels of one token. Conv weights (pre-transposed [9][96]) live in 72
// VGPRs per thread, loaded once. LN via tiny LDS reduce of 12 partials.
// TRANSPOSED: out [B][96][Lp] (for V^T); else [B][Lp][96].
// ---------------------------------------------------------------------------
template <bool TRANSPOSED, int STRIDE>
__global__ __launch_bounds__(192) void pool_ln3_kernel(
    const unsigned short* __restrict__ in, const float* __restrict__ pwt,
    const float* __restrict__ g, const float* __restrict__ beta,
    unsigned short* __restrict__ out, int Hp, int Wp, float oscale)
{
    __shared__ float2 part[192];
    __shared__ float2 mrs[16];
    const int tid = threadIdx.x;
    const int tok_l = tid / 12, c8 = tid % 12;
    const int gt = blockIdx.x * 16 + tok_l;
    const int Lp = Hp * Wp;
    const int b = gt / Lp, rem = gt % Lp;
    const int yo = rem / Wp, xo = rem % Wp;

    // per-thread conv weights: wt[tap][j] for channels c8*8+j
    float wt[9][8];
#pragma unroll
    for (int tap = 0; tap < 9; ++tap) {
        float4 w0 = *reinterpret_cast<const float4*>(pwt + tap * 96 + c8 * 8);
        float4 w1 = *reinterpret_cast<const float4*>(pwt + tap * 96 + c8 * 8 + 4);
        wt[tap][0] = w0.x; wt[tap][1] = w0.y; wt[tap][2] = w0.z; wt[tap][3] = w0.w;
        wt[tap][4] = w1.x; wt[tap][5] = w1.y; wt[tap][6] = w1.z; wt[tap][7] = w1.w;
    }

    float acc[8];
#pragma unroll
    for (int j = 0; j < 8; ++j) acc[j] = 0.f;

    const unsigned short* ib = in + (size_t)b * (H_IN * W_IN * 96) + c8 * 8;
#pragma unroll
    for (int dy = 0; dy < 3; ++dy) {
        const int iy = yo * STRIDE + dy - 1;
        if ((unsigned)iy < (unsigned)H_IN) {
#pragma unroll
            for (int dx = 0; dx < 3; ++dx) {
                const int ix = xo * STRIDE + dx - 1;
                if ((unsigned)ix < (unsigned)W_IN) {
                    const int tap = dy * 3 + dx;
                    uint4 d = *reinterpret_cast<const uint4*>(
                        ib + ((size_t)iy * W_IN + ix) * 96);
                    acc[0] += bflo(d.x) * wt[tap][0];
                    acc[1] += bfhi(d.x) * wt[tap][1];
                    acc[2] += bflo(d.y) * wt[tap][2];
                    acc[3] += bfhi(d.y) * wt[tap][3];
                    acc[4] += bflo(d.z) * wt[tap][4];
                    acc[5] += bfhi(d.z) * wt[tap][5];
                    acc[6] += bflo(d.w) * wt[tap][6];
                    acc[7] += bfhi(d.w) * wt[tap][7];
                }
            }
        }
    }

    float s = 0.f, s2 = 0.f;
#pragma unroll
    for (int j = 0; j < 8; ++j) { s += acc[j]; s2 += acc[j] * acc[j]; }
    part[tid] = make_float2(s, s2);
    __syncthreads();
    if (tid < 16) {
        float a = 0.f, q = 0.f;
#pragma unroll
        for (int j = 0; j < 12; ++j) {
            float2 p = part[tid * 12 + j];
            a += p.x; q += p.y;
        }
        float mu = a * (1.f / 96.f);
        float var = q * (1.f / 96.f) - mu * mu;
        mrs[tid] = make_float2(mu, rsqrtf(var + 1e-6f));
    }
    __syncthreads();
    const float mu = mrs[tok_l].x, rstd = mrs[tok_l].y;

    float4 g0 = *reinterpret_cast<const float4*>(g + c8 * 8);
    float4 g1 = *reinterpret_cast<const float4*>(g + c8 * 8 + 4);
    float4 b0 = *reinterpret_cast<const float4*>(beta + c8 * 8);
    float4 b1 = *reinterpret_cast<const float4*>(beta + c8 * 8 + 4);
    float r[8];
    r[0] = (acc[0] - mu) * rstd * (g0.x * oscale) + b0.x * oscale;
    r[1] = (acc[1] - mu) * rstd * (g0.y * oscale) + b0.y * oscale;
    r[2] = (acc[2] - mu) * rstd * (g0.z * oscale) + b0.z * oscale;
    r[3] = (acc[3] - mu) * rstd * (g0.w * oscale) + b0.w * oscale;
    r[4] = (acc[4] - mu) * rstd * (g1.x * oscale) + b1.x * oscale;
    r[5] = (acc[5] - mu) * rstd * (g1.y * oscale) + b1.y * oscale;
    r[6] = (acc[6] - mu) * rstd * (g1.z * oscale) + b1.z * oscale;
    r[7] = (acc[7] - mu) * rstd * (g1.w * oscale) + b1.w * oscale;

    if (!TRANSPOSED) {
        uint4 o;
        o.x = pack_bf16(r[0], r[1]); o.y = pack_bf16(r[2], r[3]);
        o.z = pack_bf16(r[4], r[5]); o.w = pack_bf16(r[6], r[7]);
        *reinterpret_cast<uint4*>(out + (size_t)gt * 96 + c8 * 8) = o;
    } else {
#pragma unroll
        for (int j = 0; j < 8; ++j)
            out[((size_t)b * 96 + c8 * 8 + j) * Lp + rem] = cvt_bf16(r[j]);
    }
}

// ---------------------------------------------------------------------------
// MFMA flash attention v2 + residual (bf16 out). 32x32x16 MFMA, 4 waves x
// 32 q = 128 q rows/block. Fixed-m softmax (scale*log2e folded into K;
// LN-bounded scores => exp2 cannot overflow). K and V^T staged in FRAGMENT
// ORDER (lane-linear 16B) -> no bank conflicts.
// ---------------------------------------------------------------------------
__global__ __launch_bounds__(256, 3) void attn_mfma2_kernel(
    const unsigned short* __restrict__ qpl, const unsigned short* __restrict__ kpl,
    const unsigned short* __restrict__ vtp, unsigned short* __restrict__ out)
{
    __shared__ unsigned short Kl[18 * 64 * 8];   // 18 KB, frag-order
    __shared__ unsigned short Vl[18 * 64 * 8];   // 18 KB, frag-order

    const int tid = threadIdx.x;
    const int wid = tid >> 6, lane = tid & 63;
    const int l31 = lane & 31, h = lane >> 5;
    const int b = blockIdx.y;
    const int qrow = blockIdx.x * 128 + wid * 32 + l31;
    const int qrl = qrow < N_IN ? qrow : N_IN - 1;

    const unsigned short* qptr = qpl + ((size_t)b * N_IN + qrl) * 96;
    bf16x8 qf[6];
#pragma unroll
    for (int kkb = 0; kkb < 6; ++kkb)
        qf[kkb] = *reinterpret_cast<const bf16x8*>(qptr + kkb * 16 + h * 8);

    f32x16 acc0 = zero16(), acc1 = zero16(), acc2 = zero16();
    float lsum = 0.f;

    const unsigned short* kg0 = kpl + (size_t)b * LKV * 96;
    const unsigned short* vg0 = vtp + (size_t)b * 96 * LKV;

    for (int ck = 0; ck < 9; ++ck) {
        const int base = ck * 96;
        __syncthreads();
        for (int idx = tid; idx < 1152; idx += 256) {
            int frag = idx >> 6, ln = idx & 63;
            int tt = frag / 6, kkb = frag % 6;
            int kv = base + tt * 32 + (ln & 31);
            int k0 = kkb * 16 + (ln >> 5) * 8;
            int4 v = make_int4(0, 0, 0, 0);
            if (kv < LKV) v = *reinterpret_cast<const int4*>(kg0 + (size_t)kv * 96 + k0);
            *reinterpret_cast<int4*>(&Kl[idx * 8]) = v;
        }
        for (int idx = tid; idx < 1152; idx += 256) {
            int frag = idx >> 6, ln = idx & 63;
            int ct = frag / 6, kb2 = frag % 6;
            int chn = ct * 32 + (ln & 31);
            int kv0 = base + kb2 * 16 + (ln >> 5) * 8;
            int4 v = make_int4(0, 0, 0, 0);
            if (kv0 < LKV) v = *reinterpret_cast<const int4*>(vg0 + (size_t)chn * LKV + kv0);
            *reinterpret_cast<int4*>(&Vl[idx * 8]) = v;
        }
        __syncthreads();

        const int ntl = (ck == 8) ? 1 : 3;
        for (int tt = 0; tt < ntl; ++tt) {
            int nval = LKV - base - tt * 32;
            if (nval > 32) nval = 32;

            f32x16 s = zero16();
#pragma unroll
            for (int kkb = 0; kkb < 6; ++kkb) {
                bf16x8 af = *reinterpret_cast<const bf16x8*>(
                    &Kl[((tt * 6 + kkb) * 64 + lane) * 8]);
                s = __builtin_amdgcn_mfma_f32_32x32x16_bf16(af, qf[kkb], s, 0, 0, 0);
            }

            float p[16];
#pragma unroll
            for (int r = 0; r < 16; ++r) {
                float e = exp2f(s[r]);
                unsigned u = __builtin_bit_cast(unsigned, e) & 0xFFFF0000u;
                p[r] = __builtin_bit_cast(float, u);
            }
            if (nval == 32) {
                float a0 = 0.f, a1 = 0.f;
#pragma unroll
                for (int r = 0; r < 8; ++r) { a0 += p[r]; a1 += p[r + 8]; }
                lsum += a0 + a1;
            } else {
                float a0 = 0.f;
#pragma unroll
                for (int r = 0; r < 8; ++r) a0 += p[r];
                lsum += a0;
            }

            unsigned d[8], sw[8];
#pragma unroll
            for (int j = 0; j < 8; ++j) d[j] = pack_trunc(p[2 * j], p[2 * j + 1]);
#pragma unroll
            for (int j = 0; j < 8; ++j) sw[j] = (unsigned)__shfl_xor((int)d[j], 32);

            {
                int4 bi = h ? make_int4((int)sw[2], (int)sw[3], (int)d[2], (int)d[3])
                            : make_int4((int)d[0], (int)d[1], (int)sw[0], (int)sw[1]);
                bf16x8 bf = __builtin_bit_cast(bf16x8, bi);
                int vf = tt * 2;
                bf16x8 a0 = *reinterpret_cast<const bf16x8*>(&Vl[((0 * 6 + vf) * 64 + lane) * 8]);
                bf16x8 a1 = *reinterpret_cast<const bf16x8*>(&Vl[((1 * 6 + vf) * 64 + lane) * 8]);
                bf16x8 a2 = *reinterpret_cast<const bf16x8*>(&Vl[((2 * 6 + vf) * 64 + lane) * 8]);
                acc0 = __builtin_amdgcn_mfma_f32_32x32x16_bf16(a0, bf, acc0, 0, 0, 0);
                acc1 = __builtin_amdgcn_mfma_f32_32x32x16_bf16(a1, bf, acc1, 0, 0, 0);
                acc2 = __builtin_amdgcn_mfma_f32_32x32x16_bf16(a2, bf, acc2, 0, 0, 0);
            }
            if (nval == 32) {
                int4 bi = h ? make_int4((int)sw[6], (int)sw[7], (int)d[6], (int)d[7])
                            : make_int4((int)d[4], (int)d[5], (int)sw[4], (int)sw[5]);
                bf16x8 bf = __builtin_bit_cast(bf16x8, bi);
                int vf = tt * 2 + 1;
                bf16x8 a0 = *reinterpret_cast<const bf16x8*>(&Vl[((0 * 6 + vf) * 64 + lane) * 8]);
                bf16x8 a1 = *reinterpret_cast<const bf16x8*>(&Vl[((1 * 6 + vf) * 64 + lane) * 8]);
                bf16x8 a2 = *reinterpret_cast<const bf16x8*>(&Vl[((2 * 6 + vf) * 64 + lane) * 8]);
                acc0 = __builtin_amdgcn_mfma_f32_32x32x16_bf16(a0, bf, acc0, 0, 0, 0);
                acc1 = __builtin_amdgcn_mfma_f32_32x32x16_bf16(a1, bf, acc1, 0, 0, 0);
                acc2 = __builtin_amdgcn_mfma_f32_32x32x16_bf16(a2, bf, acc2, 0, 0, 0);
            }
        }
    }

    lsum += __shfl_xor(lsum, 32);
    const float inv = 1.f / lsum;

    if (qrow < N_IN) {
        const unsigned short* qres = qpl + ((size_t)b * N_IN + qrow) * 96;
        unsigned short* op = out + ((size_t)b * N_IN + qrow) * 96;
#pragma unroll
        for (int ct = 0; ct < 3; ++ct) {
            const f32x16& a = (ct == 0) ? acc0 : (ct == 1 ? acc1 : acc2);
#pragma unroll
            for (int gblk = 0; gblk < 4; ++gblk) {
                int ch = ct * 32 + gblk * 8 + 4 * h;
                ushort4 q4 = *reinterpret_cast<const ushort4*>(qres + ch);
                uint2 pr;
                pr.x = pack_bf16(a[gblk * 4 + 0] * inv + bf16_to_f32(q4.x),
                                 a[gblk * 4 + 1] * inv + bf16_to_f32(q4.y));
                pr.y = pack_bf16(a[gblk * 4 + 2] * inv + bf16_to_f32(q4.z),
                                 a[gblk * 4 + 3] * inv + bf16_to_f32(q4.w));
                *reinterpret_cast<uint2*>(op + ch) = pr;
            }
        }
    }
}

// ---------------------------------------------------------------------------
extern "C" void kernel_launch(void* const* d_in, const int* in_sizes, int n_in,
                              void* d_out, int out_size, void* d_ws, size_t ws_size,
                              hipStream_t stream)
{
    const float* x     = (const float*)d_in[0];
    const float* Wqkv  = (const float*)d_in[1];
    const float* bqkv  = (const float*)d_in[2];
    const float* pqw   = (const float*)d_in[3];
    const float* gq    = (const float*)d_in[4];
    const float* betq  = (const float*)d_in[5];
    const float* pkw   = (const float*)d_in[6];
    const float* gk    = (const float*)d_in[7];
    const float* betk  = (const float*)d_in[8];
    const float* pvw   = (const float*)d_in[9];
    const float* gv    = (const float*)d_in[10];
    const float* betv  = (const float*)d_in[11];
    const float* Wproj = (const float*)d_in[12];
    const float* bproj = (const float*)d_in[13];
    float* outp = (float*)d_out;

    char* ws = (char*)d_ws;
    const size_t QB    = (size_t)BATCH * N_IN * 96 * sizeof(short);   // 19.27 MB
    const size_t KVBYT = (size_t)BATCH * LKV * 96 * sizeof(short);    // 4.8 MB
    unsigned short* qb   = (unsigned short*)(ws);
    unsigned short* kbuf = (unsigned short*)(ws + QB);
    unsigned short* vbuf = (unsigned short*)(ws + 2 * QB);
    unsigned short* qpb  = (unsigned short*)(ws + 3 * QB);
    unsigned short* kpb  = (unsigned short*)(ws + 4 * QB);
    unsigned short* vptb = (unsigned short*)(ws + 4 * QB + KVBYT);
    unsigned short* wqf  = (unsigned short*)(ws + 4 * QB + 2 * KVBYT);
    unsigned short* wpf  = (unsigned short*)(ws + 4 * QB + 2 * KVBYT + 56320);
    float*          wpool = (float*)(ws + 4 * QB + 2 * KVBYT + 56320 + 18432);
    unsigned short* attn_out = qb;   // qb dead after pool_q

    const int T = BATCH * N_IN;      // 100352 = 256 * 392

    const float SC = 0.1020620726159658f * 1.4426950408889634f; // scale*log2e

    // 0. one-time weight prep (GEMM frags + pool transposes)
    wprep_kernel<<<29, 256, 0, stream>>>(Wqkv, Wproj, pqw, pkw, pvw, wqf, wpf, wpool);
    // 1. QKV projection (MFMA) -> q,k,v bf16 [B][3136][96]
    gemm2_kernel<18, false, false><<<T / 256, 256, 0, stream>>>(
        x, wqf, bqkv, qb, kbuf, vbuf);
    // 2-4. pool v3 (conv+LN) -> bf16 (K scaled by SC, V transposed)
    pool_ln3_kernel<false, 1><<<T / 16, 192, 0, stream>>>(
        qb, wpool, gq, betq, qpb, 56, 56, 1.0f);
    pool_ln3_kernel<false, 2><<<(BATCH * LKV) / 16, 192, 0, stream>>>(
        kbuf, wpool + 864, gk, betk, kpb, 28, 28, SC);
    pool_ln3_kernel<true, 2><<<(BATCH * LKV) / 16, 192, 0, stream>>>(
        vbuf, wpool + 1728, gv, betv, vptb, 28, 28, 1.0f);
    // 5. MFMA attention v2 + residual (bf16 out)
    attn_mfma2_kernel<<<dim3(25, BATCH), 256, 0, stream>>>(qpb, kpb, vptb, attn_out);
    // 6. output projection (MFMA, fp32 out)
    gemm2_kernel<6, true, true><<<T / 256, 256, 0, stream>>>(
        attn_out, wpf, bproj, outp, nullptr, nullptr);
}

// Round 6
// 170.420 us; speedup vs baseline: 14.9011x; 1.0191x over previous
//
#include <hip/hip_runtime.h>
#include <hip/hip_bf16.h>
#include <cmath>

#define BATCH 32
#define H_IN 56
#define W_IN 56
#define N_IN (H_IN * W_IN)   // 3136
#define LKV 784              // 28*28 pooled kv length

typedef short bf16x8 __attribute__((ext_vector_type(8)));
typedef float f32x4 __attribute__((ext_vector_type(4)));
typedef float f32x16 __attribute__((ext_vector_type(16)));

__device__ __forceinline__ unsigned pack_bf16(float a, float b) {
    unsigned ua = __builtin_bit_cast(unsigned, a);
    unsigned ub = __builtin_bit_cast(unsigned, b);
    ua = (ua + 0x7FFFu + ((ua >> 16) & 1u)) >> 16;
    ub = (ub + 0x7FFFu + ((ub >> 16) & 1u)) >> 16;
    return ua | (ub << 16);
}

__device__ __forceinline__ unsigned short cvt_bf16(float a) {
    unsigned ua = __builtin_bit_cast(unsigned, a);
    return (unsigned short)((ua + 0x7FFFu + ((ua >> 16) & 1u)) >> 16);
}

__device__ __forceinline__ float bf16_to_f32(unsigned short u) {
    unsigned v = ((unsigned)u) << 16;
    return __builtin_bit_cast(float, v);
}

__device__ __forceinline__ float bflo(unsigned u) {
    return __builtin_bit_cast(float, u << 16);
}
__device__ __forceinline__ float bfhi(unsigned u) {
    return __builtin_bit_cast(float, u & 0xFFFF0000u);
}

// [lo16 = trunc-bf16(a), hi16 = trunc-bf16(b)] in one v_perm
__device__ __forceinline__ unsigned pack_trunc(float a, float b) {
    return __builtin_amdgcn_perm(__builtin_bit_cast(unsigned, b),
                                 __builtin_bit_cast(unsigned, a), 0x07060302u);
}

__device__ __forceinline__ f32x16 zero16() {
    f32x16 z;
#pragma unroll
    for (int i = 0; i < 16; ++i) z[i] = 0.f;
    return z;
}

// ---------------------------------------------------------------------------
// One-time weight prep:
//  idx <  3456 : Wqkv fp32 [288][96] -> bf16 A-frag order (54 frags)
//  idx <  4608 : Wproj fp32 [96][96] -> bf16 A-frag order (18 frags)
//  idx <  7200 : pool conv weights [96][9] -> transposed fp32 [3][9][96]
// ---------------------------------------------------------------------------
__global__ __launch_bounds__(256) void wprep_kernel(
    const float* __restrict__ Wqkv, const float* __restrict__ Wproj,
    const float* __restrict__ pqw, const float* __restrict__ pkw,
    const float* __restrict__ pvw,
    unsigned short* __restrict__ wq, unsigned short* __restrict__ wp,
    float* __restrict__ wpool)
{
    int idx = blockIdx.x * 256 + threadIdx.x;
    if (idx < 4608) {
        const float* src; unsigned short* dst; int li;
        if (idx < 3456) { src = Wqkv; dst = wq; li = idx; }
        else            { src = Wproj; dst = wp; li = idx - 3456; }
        int frag = li >> 6, ln = li & 63;
        int ct = frag / 3, kkb = frag % 3;
        int ch = ct * 16 + (ln & 15);
        int k0 = kkb * 32 + (ln >> 4) * 8;
        const float* s = src + ch * 96 + k0;
        float4 v0 = *reinterpret_cast<const float4*>(s);
        float4 v1 = *reinterpret_cast<const float4*>(s + 4);
        uint4 o;
        o.x = pack_bf16(v0.x, v0.y); o.y = pack_bf16(v0.z, v0.w);
        o.z = pack_bf16(v1.x, v1.y); o.w = pack_bf16(v1.z, v1.w);
        *reinterpret_cast<uint4*>(dst + (size_t)li * 8) = o;
    } else if (idx < 7200) {
        int li = idx - 4608;               // 0..2591
        int which = li / 864, r = li % 864;
        int tap = r / 96, c = r % 96;
        const float* src = (which == 0) ? pqw : (which == 1 ? pkw : pvw);
        wpool[which * 864 + tap * 96 + c] = src[c * 9 + tap];
    }
}

// ---------------------------------------------------------------------------
// MFMA GEMM v2: out[t][n] = sum_k X[t][k]*W[n][k] + bias[n]
// 256 thr / 4 waves; 256 tokens per block (64/wave = 4 iters x 16).
// ---------------------------------------------------------------------------
template <int NCT, bool IN_BF16, bool OUT_F32>
__global__ __launch_bounds__(256, 2) void gemm2_kernel(
    const void* __restrict__ Xv, const unsigned short* __restrict__ Wfr,
    const float* __restrict__ bias, void* __restrict__ o0,
    void* __restrict__ o1, void* __restrict__ o2)
{
    __shared__ unsigned short Wl[NCT * 192 * 8];
    const int tid = threadIdx.x;
    const int wid = tid >> 6, lane = tid & 63;
    const int lo16 = lane & 15, hi = lane >> 4;

    for (int idx = tid; idx < NCT * 192; idx += 256)
        *reinterpret_cast<int4*>(&Wl[idx * 8]) =
            *reinterpret_cast<const int4*>(Wfr + (size_t)idx * 8);

    const size_t tok0 = (size_t)blockIdx.x * 256 + wid * 64;
    bf16x8 xb[12];
#pragma unroll
    for (int it = 0; it < 4; ++it) {
        size_t t = tok0 + it * 16 + lo16;
#pragma unroll
        for (int kkb = 0; kkb < 3; ++kkb) {
            if constexpr (IN_BF16) {
                xb[it * 3 + kkb] = *reinterpret_cast<const bf16x8*>(
                    (const unsigned short*)Xv + t * 96 + kkb * 32 + hi * 8);
            } else {
                const float* xp = (const float*)Xv + t * 96 + kkb * 32 + hi * 8;
                float4 a = *reinterpret_cast<const float4*>(xp);
                float4 c = *reinterpret_cast<const float4*>(xp + 4);
                uint4 u;
                u.x = pack_bf16(a.x, a.y); u.y = pack_bf16(a.z, a.w);
                u.z = pack_bf16(c.x, c.y); u.w = pack_bf16(c.z, c.w);
                xb[it * 3 + kkb] = __builtin_bit_cast(bf16x8, u);
            }
        }
    }
    __syncthreads();

#pragma unroll
    for (int ct = 0; ct < NCT; ++ct) {
        bf16x8 wf[3];
#pragma unroll
        for (int kkb = 0; kkb < 3; ++kkb)
            wf[kkb] = *reinterpret_cast<const bf16x8*>(&Wl[((ct * 3 + kkb) * 64 + lane) * 8]);
        const int chb = ct * 16 + hi * 4;
        float4 bv = *reinterpret_cast<const float4*>(bias + chb);
#pragma unroll
        for (int it = 0; it < 4; ++it) {
            f32x4 a = (f32x4){0.f, 0.f, 0.f, 0.f};
#pragma unroll
            for (int kkb = 0; kkb < 3; ++kkb)
                a = __builtin_amdgcn_mfma_f32_16x16x32_bf16(wf[kkb], xb[it * 3 + kkb], a, 0, 0, 0);
            size_t t = tok0 + it * 16 + lo16;
            float r0 = a[0] + bv.x, r1 = a[1] + bv.y;
            float r2 = a[2] + bv.z, r3 = a[3] + bv.w;
            if constexpr (OUT_F32) {
                *reinterpret_cast<float4*>((float*)o0 + t * 96 + chb) =
                    make_float4(r0, r1, r2, r3);
            } else {
                unsigned short* ob =
                    (unsigned short*)((ct < 6) ? o0 : (ct < 12 ? o1 : o2));
                int lch = (ct % 6) * 16 + hi * 4;
                uint2 p;
                p.x = pack_bf16(r0, r1);
                p.y = pack_bf16(r2, r3);
                *reinterpret_cast<uint2*>(ob + t * 96 + lch) = p;
            }
        }
    }
}

// ---------------------------------------------------------------------------
// Pool v3: depthwise 3x3 conv (pad 1) + LayerNorm, bf16 in/out.
// Block = 192 threads = 16 tokens x 12 chunk-threads.
// ---------------------------------------------------------------------------
template <bool TRANSPOSED, int STRIDE>
__global__ __launch_bounds__(192) void pool_ln3_kernel(
    const unsigned short* __restrict__ in, const float* __restrict__ pwt,
    const float* __restrict__ g, const float* __restrict__ beta,
    unsigned short* __restrict__ out, int Hp, int Wp, float oscale)
{
    __shared__ float2 part[192];
    __shared__ float2 mrs[16];
    const int tid = threadIdx.x;
    const int tok_l = tid / 12, c8 = tid % 12;
    const int gt = blockIdx.x * 16 + tok_l;
    const int Lp = Hp * Wp;
    const int b = gt / Lp, rem = gt % Lp;
    const int yo = rem / Wp, xo = rem % Wp;

    float wt[9][8];
#pragma unroll
    for (int tap = 0; tap < 9; ++tap) {
        float4 w0 = *reinterpret_cast<const float4*>(pwt + tap * 96 + c8 * 8);
        float4 w1 = *reinterpret_cast<const float4*>(pwt + tap * 96 + c8 * 8 + 4);
        wt[tap][0] = w0.x; wt[tap][1] = w0.y; wt[tap][2] = w0.z; wt[tap][3] = w0.w;
        wt[tap][4] = w1.x; wt[tap][5] = w1.y; wt[tap][6] = w1.z; wt[tap][7] = w1.w;
    }

    float acc[8];
#pragma unroll
    for (int j = 0; j < 8; ++j) acc[j] = 0.f;

    const unsigned short* ib = in + (size_t)b * (H_IN * W_IN * 96) + c8 * 8;
#pragma unroll
    for (int dy = 0; dy < 3; ++dy) {
        const int iy = yo * STRIDE + dy - 1;
        if ((unsigned)iy < (unsigned)H_IN) {
#pragma unroll
            for (int dx = 0; dx < 3; ++dx) {
                const int ix = xo * STRIDE + dx - 1;
                if ((unsigned)ix < (unsigned)W_IN) {
                    const int tap = dy * 3 + dx;
                    uint4 d = *reinterpret_cast<const uint4*>(
                        ib + ((size_t)iy * W_IN + ix) * 96);
                    acc[0] += bflo(d.x) * wt[tap][0];
                    acc[1] += bfhi(d.x) * wt[tap][1];
                    acc[2] += bflo(d.y) * wt[tap][2];
                    acc[3] += bfhi(d.y) * wt[tap][3];
                    acc[4] += bflo(d.z) * wt[tap][4];
                    acc[5] += bfhi(d.z) * wt[tap][5];
                    acc[6] += bflo(d.w) * wt[tap][6];
                    acc[7] += bfhi(d.w) * wt[tap][7];
                }
            }
        }
    }

    float s = 0.f, s2 = 0.f;
#pragma unroll
    for (int j = 0; j < 8; ++j) { s += acc[j]; s2 += acc[j] * acc[j]; }
    part[tid] = make_float2(s, s2);
    __syncthreads();
    if (tid < 16) {
        float a = 0.f, q = 0.f;
#pragma unroll
        for (int j = 0; j < 12; ++j) {
            float2 p = part[tid * 12 + j];
            a += p.x; q += p.y;
        }
        float mu = a * (1.f / 96.f);
        float var = q * (1.f / 96.f) - mu * mu;
        mrs[tid] = make_float2(mu, rsqrtf(var + 1e-6f));
    }
    __syncthreads();
    const float mu = mrs[tok_l].x, rstd = mrs[tok_l].y;

    float4 g0 = *reinterpret_cast<const float4*>(g + c8 * 8);
    float4 g1 = *reinterpret_cast<const float4*>(g + c8 * 8 + 4);
    float4 b0 = *reinterpret_cast<const float4*>(beta + c8 * 8);
    float4 b1 = *reinterpret_cast<const float4*>(beta + c8 * 8 + 4);
    float r[8];
    r[0] = (acc[0] - mu) * rstd * (g0.x * oscale) + b0.x * oscale;
    r[1] = (acc[1] - mu) * rstd * (g0.y * oscale) + b0.y * oscale;
    r[2] = (acc[2] - mu) * rstd * (g0.z * oscale) + b0.z * oscale;
    r[3] = (acc[3] - mu) * rstd * (g0.w * oscale) + b0.w * oscale;
    r[4] = (acc[4] - mu) * rstd * (g1.x * oscale) + b1.x * oscale;
    r[5] = (acc[5] - mu) * rstd * (g1.y * oscale) + b1.y * oscale;
    r[6] = (acc[6] - mu) * rstd * (g1.z * oscale) + b1.z * oscale;
    r[7] = (acc[7] - mu) * rstd * (g1.w * oscale) + b1.w * oscale;

    if (!TRANSPOSED) {
        uint4 o;
        o.x = pack_bf16(r[0], r[1]); o.y = pack_bf16(r[2], r[3]);
        o.z = pack_bf16(r[4], r[5]); o.w = pack_bf16(r[6], r[7]);
        *reinterpret_cast<uint4*>(out + (size_t)gt * 96 + c8 * 8) = o;
    } else {
#pragma unroll
        for (int j = 0; j < 8; ++j)
            out[((size_t)b * 96 + c8 * 8 + j) * Lp + rem] = cvt_bf16(r[j]);
    }
}

// ---------------------------------------------------------------------------
// MFMA flash attention v3 + residual (bf16 out). 32x32x16 MFMA.
// 4 waves x 64 q (2 groups of 32) = 256 q rows/block. Each K/V LDS frag
// read feeds 2 MFMAs (one per q-group) -> LDS reads per score halved,
// 2x independent accumulator chains hide MFMA latency.
// Fixed-m softmax via v_exp (__builtin_amdgcn_exp2f); scale*log2e folded
// into K so scores are LN-bounded (|s|<=14.1) -> no range handling needed.
// ---------------------------------------------------------------------------
__global__ __launch_bounds__(256, 2) void attn_mfma3_kernel(
    const unsigned short* __restrict__ qpl, const unsigned short* __restrict__ kpl,
    const unsigned short* __restrict__ vtp, unsigned short* __restrict__ out)
{
    __shared__ unsigned short Kl[18 * 64 * 8];   // 18 KB, frag-order
    __shared__ unsigned short Vl[18 * 64 * 8];   // 18 KB, frag-order

    const int tid = threadIdx.x;
    const int wid = tid >> 6, lane = tid & 63;
    const int l31 = lane & 31, h = lane >> 5;
    const int b = blockIdx.y;
    const int qbase = blockIdx.x * 256 + wid * 64;

    const int qrowA = qbase + l31;
    const int qrowB = qbase + 32 + l31;
    const int qrlA = qrowA < N_IN ? qrowA : N_IN - 1;
    const int qrlB = qrowB < N_IN ? qrowB : N_IN - 1;
    const unsigned short* qptrA = qpl + ((size_t)b * N_IN + qrlA) * 96;
    const unsigned short* qptrB = qpl + ((size_t)b * N_IN + qrlB) * 96;
    bf16x8 qfA[6], qfB[6];
#pragma unroll
    for (int kkb = 0; kkb < 6; ++kkb) {
        qfA[kkb] = *reinterpret_cast<const bf16x8*>(qptrA + kkb * 16 + h * 8);
        qfB[kkb] = *reinterpret_cast<const bf16x8*>(qptrB + kkb * 16 + h * 8);
    }

    f32x16 aA[3], aB[3];
#pragma unroll
    for (int ct = 0; ct < 3; ++ct) { aA[ct] = zero16(); aB[ct] = zero16(); }
    float lA = 0.f, lB = 0.f;

    const unsigned short* kg0 = kpl + (size_t)b * LKV * 96;
    const unsigned short* vg0 = vtp + (size_t)b * 96 * LKV;

    for (int ck = 0; ck < 9; ++ck) {
        const int base = ck * 96;
        __syncthreads();
        for (int idx = tid; idx < 1152; idx += 256) {
            int frag = idx >> 6, ln = idx & 63;
            int tt = frag / 6, kkb = frag % 6;
            int kv = base + tt * 32 + (ln & 31);
            int k0 = kkb * 16 + (ln >> 5) * 8;
            int4 v = make_int4(0, 0, 0, 0);
            if (kv < LKV) v = *reinterpret_cast<const int4*>(kg0 + (size_t)kv * 96 + k0);
            *reinterpret_cast<int4*>(&Kl[idx * 8]) = v;
        }
        for (int idx = tid; idx < 1152; idx += 256) {
            int frag = idx >> 6, ln = idx & 63;
            int ct = frag / 6, kb2 = frag % 6;
            int chn = ct * 32 + (ln & 31);
            int kv0 = base + kb2 * 16 + (ln >> 5) * 8;
            int4 v = make_int4(0, 0, 0, 0);
            if (kv0 < LKV) v = *reinterpret_cast<const int4*>(vg0 + (size_t)chn * LKV + kv0);
            *reinterpret_cast<int4*>(&Vl[idx * 8]) = v;
        }
        __syncthreads();

        const int ntl = (ck == 8) ? 1 : 3;
        for (int tt = 0; tt < ntl; ++tt) {
            int nval = LKV - base - tt * 32;
            if (nval > 32) nval = 32;

            // S^T tiles for both q-groups; each K frag read feeds 2 mfmas
            f32x16 sA = zero16(), sB = zero16();
#pragma unroll
            for (int kkb = 0; kkb < 6; ++kkb) {
                bf16x8 af = *reinterpret_cast<const bf16x8*>(
                    &Kl[((tt * 6 + kkb) * 64 + lane) * 8]);
                sA = __builtin_amdgcn_mfma_f32_32x32x16_bf16(af, qfA[kkb], sA, 0, 0, 0);
                sB = __builtin_amdgcn_mfma_f32_32x32x16_bf16(af, qfB[kkb], sB, 0, 0, 0);
            }

            // softmax (fixed-m): p = exp2(s) via v_exp, truncated to bf16
            unsigned dA[8], dB[8], swA[8], swB[8];
            {
                float p[16];
#pragma unroll
                for (int r = 0; r < 16; ++r) {
                    float e = __builtin_amdgcn_exp2f(sA[r]);
                    p[r] = __builtin_bit_cast(float,
                             __builtin_bit_cast(unsigned, e) & 0xFFFF0000u);
                }
                if (nval == 32) {
                    float a0 = 0.f, a1 = 0.f;
#pragma unroll
                    for (int r = 0; r < 8; ++r) { a0 += p[r]; a1 += p[r + 8]; }
                    lA += a0 + a1;
                } else {
                    float a0 = 0.f;
#pragma unroll
                    for (int r = 0; r < 8; ++r) a0 += p[r];
                    lA += a0;
                }
#pragma unroll
                for (int j = 0; j < 8; ++j) dA[j] = pack_trunc(p[2 * j], p[2 * j + 1]);
            }
            {
                float p[16];
#pragma unroll
                for (int r = 0; r < 16; ++r) {
                    float e = __builtin_amdgcn_exp2f(sB[r]);
                    p[r] = __builtin_bit_cast(float,
                             __builtin_bit_cast(unsigned, e) & 0xFFFF0000u);
                }
                if (nval == 32) {
                    float a0 = 0.f, a1 = 0.f;
#pragma unroll
                    for (int r = 0; r < 8; ++r) { a0 += p[r]; a1 += p[r + 8]; }
                    lB += a0 + a1;
                } else {
                    float a0 = 0.f;
#pragma unroll
                    for (int r = 0; r < 8; ++r) a0 += p[r];
                    lB += a0;
                }
#pragma unroll
                for (int j = 0; j < 8; ++j) dB[j] = pack_trunc(p[2 * j], p[2 * j + 1]);
            }
#pragma unroll
            for (int j = 0; j < 8; ++j) {
                swA[j] = (unsigned)__shfl_xor((int)dA[j], 32);
                swB[j] = (unsigned)__shfl_xor((int)dB[j], 32);
            }

            // PV kv-block 0; each V frag read feeds 2 mfmas
            {
                int4 biA = h ? make_int4((int)swA[2], (int)swA[3], (int)dA[2], (int)dA[3])
                             : make_int4((int)dA[0], (int)dA[1], (int)swA[0], (int)swA[1]);
                int4 biB = h ? make_int4((int)swB[2], (int)swB[3], (int)dB[2], (int)dB[3])
                             : make_int4((int)dB[0], (int)dB[1], (int)swB[0], (int)swB[1]);
                bf16x8 bfA = __builtin_bit_cast(bf16x8, biA);
                bf16x8 bfB = __builtin_bit_cast(bf16x8, biB);
                int vf = tt * 2;
#pragma unroll
                for (int ct = 0; ct < 3; ++ct) {
                    bf16x8 av = *reinterpret_cast<const bf16x8*>(
                        &Vl[((ct * 6 + vf) * 64 + lane) * 8]);
                    aA[ct] = __builtin_amdgcn_mfma_f32_32x32x16_bf16(av, bfA, aA[ct], 0, 0, 0);
                    aB[ct] = __builtin_amdgcn_mfma_f32_32x32x16_bf16(av, bfB, aB[ct], 0, 0, 0);
                }
            }
            // PV kv-block 1 (skipped in padded tail)
            if (nval == 32) {
                int4 biA = h ? make_int4((int)swA[6], (int)swA[7], (int)dA[6], (int)dA[7])
                             : make_int4((int)dA[4], (int)dA[5], (int)swA[4], (int)swA[5]);
                int4 biB = h ? make_int4((int)swB[6], (int)swB[7], (int)dB[6], (int)dB[7])
                             : make_int4((int)dB[4], (int)dB[5], (int)swB[4], (int)swB[5]);
                bf16x8 bfA = __builtin_bit_cast(bf16x8, biA);
                bf16x8 bfB = __builtin_bit_cast(bf16x8, biB);
                int vf = tt * 2 + 1;
#pragma unroll
                for (int ct = 0; ct < 3; ++ct) {
                    bf16x8 av = *reinterpret_cast<const bf16x8*>(
                        &Vl[((ct * 6 + vf) * 64 + lane) * 8]);
                    aA[ct] = __builtin_amdgcn_mfma_f32_32x32x16_bf16(av, bfA, aA[ct], 0, 0, 0);
                    aB[ct] = __builtin_amdgcn_mfma_f32_32x32x16_bf16(av, bfB, aB[ct], 0, 0, 0);
                }
            }
        }
    }

    lA += __shfl_xor(lA, 32);
    lB += __shfl_xor(lB, 32);
    const float invA = 1.f / lA;
    const float invB = 1.f / lB;

    if (qrowA < N_IN) {
        const unsigned short* qres = qpl + ((size_t)b * N_IN + qrowA) * 96;
        unsigned short* op = out + ((size_t)b * N_IN + qrowA) * 96;
#pragma unroll
        for (int ct = 0; ct < 3; ++ct) {
#pragma unroll
            for (int gblk = 0; gblk < 4; ++gblk) {
                int ch = ct * 32 + gblk * 8 + 4 * h;
                ushort4 q4 = *reinterpret_cast<const ushort4*>(qres + ch);
                uint2 pr;
                pr.x = pack_bf16(aA[ct][gblk * 4 + 0] * invA + bf16_to_f32(q4.x),
                                 aA[ct][gblk * 4 + 1] * invA + bf16_to_f32(q4.y));
                pr.y = pack_bf16(aA[ct][gblk * 4 + 2] * invA + bf16_to_f32(q4.z),
                                 aA[ct][gblk * 4 + 3] * invA + bf16_to_f32(q4.w));
                *reinterpret_cast<uint2*>(op + ch) = pr;
            }
        }
    }
    if (qrowB < N_IN) {
        const unsigned short* qres = qpl + ((size_t)b * N_IN + qrowB) * 96;
        unsigned short* op = out + ((size_t)b * N_IN + qrowB) * 96;
#pragma unroll
        for (int ct = 0; ct < 3; ++ct) {
#pragma unroll
            for (int gblk = 0; gblk < 4; ++gblk) {
                int ch = ct * 32 + gblk * 8 + 4 * h;
                ushort4 q4 = *reinterpret_cast<const ushort4*>(qres + ch);
                uint2 pr;
                pr.x = pack_bf16(aB[ct][gblk * 4 + 0] * invB + bf16_to_f32(q4.x),
                                 aB[ct][gblk * 4 + 1] * invB + bf16_to_f32(q4.y));
                pr.y = pack_bf16(aB[ct][gblk * 4 + 2] * invB + bf16_to_f32(q4.z),
                                 aB[ct][gblk * 4 + 3] * invB + bf16_to_f32(q4.w));
                *reinterpret_cast<uint2*>(op + ch) = pr;
            }
        }
    }
}

// ---------------------------------------------------------------------------
extern "C" void kernel_launch(void* const* d_in, const int* in_sizes, int n_in,
                              void* d_out, int out_size, void* d_ws, size_t ws_size,
                              hipStream_t stream)
{
    const float* x     = (const float*)d_in[0];
    const float* Wqkv  = (const float*)d_in[1];
    const float* bqkv  = (const float*)d_in[2];
    const float* pqw   = (const float*)d_in[3];
    const float* gq    = (const float*)d_in[4];
    const float* betq  = (const float*)d_in[5];
    const float* pkw   = (const float*)d_in[6];
    const float* gk    = (const float*)d_in[7];
    const float* betk  = (const float*)d_in[8];
    const float* pvw   = (const float*)d_in[9];
    const float* gv    = (const float*)d_in[10];
    const float* betv  = (const float*)d_in[11];
    const float* Wproj = (const float*)d_in[12];
    const float* bproj = (const float*)d_in[13];
    float* outp = (float*)d_out;

    char* ws = (char*)d_ws;
    const size_t QB    = (size_t)BATCH * N_IN * 96 * sizeof(short);   // 19.27 MB
    const size_t KVBYT = (size_t)BATCH * LKV * 96 * sizeof(short);    // 4.8 MB
    unsigned short* qb   = (unsigned short*)(ws);
    unsigned short* kbuf = (unsigned short*)(ws + QB);
    unsigned short* vbuf = (unsigned short*)(ws + 2 * QB);
    unsigned short* qpb  = (unsigned short*)(ws + 3 * QB);
    unsigned short* kpb  = (unsigned short*)(ws + 4 * QB);
    unsigned short* vptb = (unsigned short*)(ws + 4 * QB + KVBYT);
    unsigned short* wqf  = (unsigned short*)(ws + 4 * QB + 2 * KVBYT);
    unsigned short* wpf  = (unsigned short*)(ws + 4 * QB + 2 * KVBYT + 56320);
    float*          wpool = (float*)(ws + 4 * QB + 2 * KVBYT + 56320 + 18432);
    unsigned short* attn_out = qb;   // qb dead after pool_q

    const int T = BATCH * N_IN;      // 100352 = 256 * 392

    const float SC = 0.1020620726159658f * 1.4426950408889634f; // scale*log2e

    // 0. one-time weight prep (GEMM frags + pool transposes)
    wprep_kernel<<<29, 256, 0, stream>>>(Wqkv, Wproj, pqw, pkw, pvw, wqf, wpf, wpool);
    // 1. QKV projection (MFMA) -> q,k,v bf16 [B][3136][96]
    gemm2_kernel<18, false, false><<<T / 256, 256, 0, stream>>>(
        x, wqf, bqkv, qb, kbuf, vbuf);
    // 2-4. pool v3 (conv+LN) -> bf16 (K scaled by SC, V transposed)
    pool_ln3_kernel<false, 1><<<T / 16, 192, 0, stream>>>(
        qb, wpool, gq, betq, qpb, 56, 56, 1.0f);
    pool_ln3_kernel<false, 2><<<(BATCH * LKV) / 16, 192, 0, stream>>>(
        kbuf, wpool + 864, gk, betk, kpb, 2 * 14, 28, SC);
    pool_ln3_kernel<true, 2><<<(BATCH * LKV) / 16, 192, 0, stream>>>(
        vbuf, wpool + 1728, gv, betv, vptb, 28, 28, 1.0f);
    // 5. MFMA attention v3 + residual (bf16 out); 256 q/block -> 13 blocks
    attn_mfma3_kernel<<<dim3((N_IN + 255) / 256, BATCH), 256, 0, stream>>>(
        qpb, kpb, vptb, attn_out);
    // 6. output projection (MFMA, fp32 out)
    gemm2_kernel<6, true, true><<<T / 256, 256, 0, stream>>>(
        attn_out, wpf, bproj, outp, nullptr, nullptr);
}

// Round 7
// 164.263 us; speedup vs baseline: 15.4596x; 1.0375x over previous
//
#include <hip/hip_runtime.h>
#include <hip/hip_bf16.h>
#include <cmath>

#define BATCH 32
#define H_IN 56
#define W_IN 56
#define N_IN (H_IN * W_IN)   // 3136
#define LKV 784              // 28*28 pooled kv length
#define LKV_PAD 864          // 27 tiles of 32
#define FRAG_ELEMS 82944     // per-batch K/V frag buffer elems (27*6*512)

typedef short bf16x8 __attribute__((ext_vector_type(8)));
typedef float f32x4 __attribute__((ext_vector_type(4)));
typedef float f32x16 __attribute__((ext_vector_type(16)));

__device__ __forceinline__ unsigned pack_bf16(float a, float b) {
    unsigned ua = __builtin_bit_cast(unsigned, a);
    unsigned ub = __builtin_bit_cast(unsigned, b);
    ua = (ua + 0x7FFFu + ((ua >> 16) & 1u)) >> 16;
    ub = (ub + 0x7FFFu + ((ub >> 16) & 1u)) >> 16;
    return ua | (ub << 16);
}

__device__ __forceinline__ unsigned short cvt_bf16(float a) {
    unsigned ua = __builtin_bit_cast(unsigned, a);
    return (unsigned short)((ua + 0x7FFFu + ((ua >> 16) & 1u)) >> 16);
}

__device__ __forceinline__ float bf16_to_f32(unsigned short u) {
    unsigned v = ((unsigned)u) << 16;
    return __builtin_bit_cast(float, v);
}

__device__ __forceinline__ float bflo(unsigned u) {
    return __builtin_bit_cast(float, u << 16);
}
__device__ __forceinline__ float bfhi(unsigned u) {
    return __builtin_bit_cast(float, u & 0xFFFF0000u);
}

// [lo16 = trunc-bf16(a), hi16 = trunc-bf16(b)] in one v_perm
__device__ __forceinline__ unsigned pack_trunc(float a, float b) {
    return __builtin_amdgcn_perm(__builtin_bit_cast(unsigned, b),
                                 __builtin_bit_cast(unsigned, a), 0x07060302u);
}

__device__ __forceinline__ f32x16 zero16() {
    f32x16 z;
#pragma unroll
    for (int i = 0; i < 16; ++i) z[i] = 0.f;
    return z;
}

// ---------------------------------------------------------------------------
// One-time weight prep:
//  idx <  3456 : Wqkv fp32 [288][96] -> bf16 A-frag order (54 frags)
//  idx <  4608 : Wproj fp32 [96][96] -> bf16 A-frag order (18 frags)
//  idx <  7200 : pool conv weights [96][9] -> transposed fp32 [3][9][96]
// ---------------------------------------------------------------------------
__global__ __launch_bounds__(256) void wprep_kernel(
    const float* __restrict__ Wqkv, const float* __restrict__ Wproj,
    const float* __restrict__ pqw, const float* __restrict__ pkw,
    const float* __restrict__ pvw,
    unsigned short* __restrict__ wq, unsigned short* __restrict__ wp,
    float* __restrict__ wpool)
{
    int idx = blockIdx.x * 256 + threadIdx.x;
    if (idx < 4608) {
        const float* src; unsigned short* dst; int li;
        if (idx < 3456) { src = Wqkv; dst = wq; li = idx; }
        else            { src = Wproj; dst = wp; li = idx - 3456; }
        int frag = li >> 6, ln = li & 63;
        int ct = frag / 3, kkb = frag % 3;
        int ch = ct * 16 + (ln & 15);
        int k0 = kkb * 32 + (ln >> 4) * 8;
        const float* s = src + ch * 96 + k0;
        float4 v0 = *reinterpret_cast<const float4*>(s);
        float4 v1 = *reinterpret_cast<const float4*>(s + 4);
        uint4 o;
        o.x = pack_bf16(v0.x, v0.y); o.y = pack_bf16(v0.z, v0.w);
        o.z = pack_bf16(v1.x, v1.y); o.w = pack_bf16(v1.z, v1.w);
        *reinterpret_cast<uint4*>(dst + (size_t)li * 8) = o;
    } else if (idx < 7200) {
        int li = idx - 4608;               // 0..2591
        int which = li / 864, r = li % 864;
        int tap = r / 96, c = r % 96;
        const float* src = (which == 0) ? pqw : (which == 1 ? pkw : pvw);
        wpool[which * 864 + tap * 96 + c] = src[c * 9 + tap];
    }
}

// ---------------------------------------------------------------------------
// MFMA GEMM v2: out[t][n] = sum_k X[t][k]*W[n][k] + bias[n]
// 256 thr / 4 waves; 256 tokens per block (64/wave = 4 iters x 16).
// ---------------------------------------------------------------------------
template <int NCT, bool IN_BF16, bool OUT_F32>
__global__ __launch_bounds__(256, 2) void gemm2_kernel(
    const void* __restrict__ Xv, const unsigned short* __restrict__ Wfr,
    const float* __restrict__ bias, void* __restrict__ o0,
    void* __restrict__ o1, void* __restrict__ o2)
{
    __shared__ unsigned short Wl[NCT * 192 * 8];
    const int tid = threadIdx.x;
    const int wid = tid >> 6, lane = tid & 63;
    const int lo16 = lane & 15, hi = lane >> 4;

    for (int idx = tid; idx < NCT * 192; idx += 256)
        *reinterpret_cast<int4*>(&Wl[idx * 8]) =
            *reinterpret_cast<const int4*>(Wfr + (size_t)idx * 8);

    const size_t tok0 = (size_t)blockIdx.x * 256 + wid * 64;
    bf16x8 xb[12];
#pragma unroll
    for (int it = 0; it < 4; ++it) {
        size_t t = tok0 + it * 16 + lo16;
#pragma unroll
        for (int kkb = 0; kkb < 3; ++kkb) {
            if constexpr (IN_BF16) {
                xb[it * 3 + kkb] = *reinterpret_cast<const bf16x8*>(
                    (const unsigned short*)Xv + t * 96 + kkb * 32 + hi * 8);
            } else {
                const float* xp = (const float*)Xv + t * 96 + kkb * 32 + hi * 8;
                float4 a = *reinterpret_cast<const float4*>(xp);
                float4 c = *reinterpret_cast<const float4*>(xp + 4);
                uint4 u;
                u.x = pack_bf16(a.x, a.y); u.y = pack_bf16(a.z, a.w);
                u.z = pack_bf16(c.x, c.y); u.w = pack_bf16(c.z, c.w);
                xb[it * 3 + kkb] = __builtin_bit_cast(bf16x8, u);
            }
        }
    }
    __syncthreads();

#pragma unroll
    for (int ct = 0; ct < NCT; ++ct) {
        bf16x8 wf[3];
#pragma unroll
        for (int kkb = 0; kkb < 3; ++kkb)
            wf[kkb] = *reinterpret_cast<const bf16x8*>(&Wl[((ct * 3 + kkb) * 64 + lane) * 8]);
        const int chb = ct * 16 + hi * 4;
        float4 bv = *reinterpret_cast<const float4*>(bias + chb);
#pragma unroll
        for (int it = 0; it < 4; ++it) {
            f32x4 a = (f32x4){0.f, 0.f, 0.f, 0.f};
#pragma unroll
            for (int kkb = 0; kkb < 3; ++kkb)
                a = __builtin_amdgcn_mfma_f32_16x16x32_bf16(wf[kkb], xb[it * 3 + kkb], a, 0, 0, 0);
            size_t t = tok0 + it * 16 + lo16;
            float r0 = a[0] + bv.x, r1 = a[1] + bv.y;
            float r2 = a[2] + bv.z, r3 = a[3] + bv.w;
            if constexpr (OUT_F32) {
                *reinterpret_cast<float4*>((float*)o0 + t * 96 + chb) =
                    make_float4(r0, r1, r2, r3);
            } else {
                unsigned short* ob =
                    (unsigned short*)((ct < 6) ? o0 : (ct < 12 ? o1 : o2));
                int lch = (ct % 6) * 16 + hi * 4;
                uint2 p;
                p.x = pack_bf16(r0, r1);
                p.y = pack_bf16(r2, r3);
                *reinterpret_cast<uint2*>(ob + t * 96 + lch) = p;
            }
        }
    }
}

// ---------------------------------------------------------------------------
// Pool v4: depthwise 3x3 conv (pad 1) + LayerNorm, bf16 in / bf16 out.
// Block = 192 threads = 16 tokens x 12 chunk-threads (8 ch each).
// OMODE 0: row-major [B][Lp][96] (q). OMODE 1: K MFMA-frag order.
// OMODE 2: V^T MFMA-frag order. For OMODE 1/2 the token space is padded to
// LpPad=864/batch; pad tokens write ZERO frags (consumed as masked pads).
// ---------------------------------------------------------------------------
template <int OMODE, int STRIDE>
__global__ __launch_bounds__(192) void pool_ln4_kernel(
    const unsigned short* __restrict__ in, const float* __restrict__ pwt,
    const float* __restrict__ g, const float* __restrict__ beta,
    unsigned short* __restrict__ out, int Hp, int Wp, int LpPad, float oscale)
{
    __shared__ float2 part[192];
    __shared__ float2 mrs[16];
    const int tid = threadIdx.x;
    const int tok_l = tid / 12, c8 = tid % 12;
    const int gt = blockIdx.x * 16 + tok_l;
    const int Lp = Hp * Wp;
    const int b = gt / LpPad, rem = gt % LpPad;
    const bool pad = (rem >= Lp);
    const int yo = rem / Wp, xo = rem % Wp;

    float wt[9][8];
#pragma unroll
    for (int tap = 0; tap < 9; ++tap) {
        float4 w0 = *reinterpret_cast<const float4*>(pwt + tap * 96 + c8 * 8);
        float4 w1 = *reinterpret_cast<const float4*>(pwt + tap * 96 + c8 * 8 + 4);
        wt[tap][0] = w0.x; wt[tap][1] = w0.y; wt[tap][2] = w0.z; wt[tap][3] = w0.w;
        wt[tap][4] = w1.x; wt[tap][5] = w1.y; wt[tap][6] = w1.z; wt[tap][7] = w1.w;
    }

    float acc[8];
#pragma unroll
    for (int j = 0; j < 8; ++j) acc[j] = 0.f;

    const unsigned short* ib = in + (size_t)b * (H_IN * W_IN * 96) + c8 * 8;
#pragma unroll
    for (int dy = 0; dy < 3; ++dy) {
        const int iy = yo * STRIDE + dy - 1;
        if ((unsigned)iy < (unsigned)H_IN) {
#pragma unroll
            for (int dx = 0; dx < 3; ++dx) {
                const int ix = xo * STRIDE + dx - 1;
                if ((unsigned)ix < (unsigned)W_IN) {
                    const int tap = dy * 3 + dx;
                    uint4 d = *reinterpret_cast<const uint4*>(
                        ib + ((size_t)iy * W_IN + ix) * 96);
                    acc[0] += bflo(d.x) * wt[tap][0];
                    acc[1] += bfhi(d.x) * wt[tap][1];
                    acc[2] += bflo(d.y) * wt[tap][2];
                    acc[3] += bfhi(d.y) * wt[tap][3];
                    acc[4] += bflo(d.z) * wt[tap][4];
                    acc[5] += bfhi(d.z) * wt[tap][5];
                    acc[6] += bflo(d.w) * wt[tap][6];
                    acc[7] += bfhi(d.w) * wt[tap][7];
                }
            }
        }
    }

    float s = 0.f, s2 = 0.f;
#pragma unroll
    for (int j = 0; j < 8; ++j) { s += acc[j]; s2 += acc[j] * acc[j]; }
    part[tid] = make_float2(s, s2);
    __syncthreads();
    if (tid < 16) {
        float a = 0.f, q = 0.f;
#pragma unroll
        for (int j = 0; j < 12; ++j) {
            float2 p = part[tid * 12 + j];
            a += p.x; q += p.y;
        }
        float mu = a * (1.f / 96.f);
        float var = q * (1.f / 96.f) - mu * mu;
        mrs[tid] = make_float2(mu, rsqrtf(var + 1e-6f));
    }
    __syncthreads();
    const float mu = mrs[tok_l].x, rstd = mrs[tok_l].y;

    float4 g0 = *reinterpret_cast<const float4*>(g + c8 * 8);
    float4 g1 = *reinterpret_cast<const float4*>(g + c8 * 8 + 4);
    float4 b0 = *reinterpret_cast<const float4*>(beta + c8 * 8);
    float4 b1 = *reinterpret_cast<const float4*>(beta + c8 * 8 + 4);
    float r[8];
    r[0] = (acc[0] - mu) * rstd * (g0.x * oscale) + b0.x * oscale;
    r[1] = (acc[1] - mu) * rstd * (g0.y * oscale) + b0.y * oscale;
    r[2] = (acc[2] - mu) * rstd * (g0.z * oscale) + b0.z * oscale;
    r[3] = (acc[3] - mu) * rstd * (g0.w * oscale) + b0.w * oscale;
    r[4] = (acc[4] - mu) * rstd * (g1.x * oscale) + b1.x * oscale;
    r[5] = (acc[5] - mu) * rstd * (g1.y * oscale) + b1.y * oscale;
    r[6] = (acc[6] - mu) * rstd * (g1.z * oscale) + b1.z * oscale;
    r[7] = (acc[7] - mu) * rstd * (g1.w * oscale) + b1.w * oscale;
    if (OMODE != 0 && pad) {
#pragma unroll
        for (int j = 0; j < 8; ++j) r[j] = 0.f;
    }

    if constexpr (OMODE == 0) {
        uint4 o;
        o.x = pack_bf16(r[0], r[1]); o.y = pack_bf16(r[2], r[3]);
        o.z = pack_bf16(r[4], r[5]); o.w = pack_bf16(r[6], r[7]);
        *reinterpret_cast<uint4*>(out + (size_t)gt * 96 + c8 * 8) = o;
    } else if constexpr (OMODE == 1) {
        // K frag order: frag(t=kv/32, kkb), lane = (kv&31)|(hi<<5); 16B/thread
        int t = rem >> 5, kkb = c8 >> 1, hi = c8 & 1;
        int ln = (rem & 31) | (hi << 5);
        uint4 o;
        o.x = pack_bf16(r[0], r[1]); o.y = pack_bf16(r[2], r[3]);
        o.z = pack_bf16(r[4], r[5]); o.w = pack_bf16(r[6], r[7]);
        *reinterpret_cast<uint4*>(out + (size_t)b * FRAG_ELEMS +
                                  ((size_t)(t * 6 + kkb) * 64 + ln) * 8) = o;
    } else {
        // V^T frag order: frag(kv16, ct), lane=(ch&31)|(lh<<5), elem = kv&7
        int kv16 = rem >> 4, e = rem & 7, lh = (rem >> 3) & 1;
#pragma unroll
        for (int j = 0; j < 8; ++j) {
            int j8 = c8 * 8 + j;
            int ct = j8 >> 5;
            int ln = (j8 & 31) | (lh << 5);
            out[(size_t)b * FRAG_ELEMS + ((size_t)(kv16 * 3 + ct) * 64 + ln) * 8 + e] =
                cvt_bf16(r[j]);
        }
    }
}

// ---------------------------------------------------------------------------
// MFMA flash attention v4 + residual (bf16 out). Barrier-free: one wave
// (64 thr) per 64 q rows; K/V read as lane-linear MFMA fragments straight
// from global (L2-resident, pre-arranged by the pools). No LDS, no syncs.
// Fixed-m softmax via v_exp; KV padded to 864 with zero frags (pad p=1
// masked from l by the r<8 rule on tile 24; pad V=0 kills PV terms).
// XCD-bijective swizzle: each XCD works 4 batches -> 1.3 MB L2 set.
// ---------------------------------------------------------------------------
__global__ __launch_bounds__(64) void attn_mfma4_kernel(
    const unsigned short* __restrict__ qpl, const unsigned short* __restrict__ Kf,
    const unsigned short* __restrict__ Vf, unsigned short* __restrict__ out)
{
    const int bid = blockIdx.x;                    // 0..1567
    const int swz = (bid & 7) * 196 + (bid >> 3);  // XCD grouping (1568%8==0)
    const int b = swz / 49, qblk = swz % 49;
    const int lane = threadIdx.x;
    const int l31 = lane & 31, h = lane >> 5;

    const int qrowA = qblk * 64 + l31;
    const int qrowB = qrowA + 32;
    const unsigned short* qptrA = qpl + ((size_t)b * N_IN + qrowA) * 96;
    const unsigned short* qptrB = qpl + ((size_t)b * N_IN + qrowB) * 96;
    bf16x8 qfA[6], qfB[6];
#pragma unroll
    for (int kkb = 0; kkb < 6; ++kkb) {
        qfA[kkb] = *reinterpret_cast<const bf16x8*>(qptrA + kkb * 16 + h * 8);
        qfB[kkb] = *reinterpret_cast<const bf16x8*>(qptrB + kkb * 16 + h * 8);
    }

    f32x16 aA0 = zero16(), aA1 = zero16(), aA2 = zero16();
    f32x16 aB0 = zero16(), aB1 = zero16(), aB2 = zero16();
    float lA = 0.f, lB = 0.f;

    const unsigned short* Kb = Kf + (size_t)b * FRAG_ELEMS;
    const unsigned short* Vb = Vf + (size_t)b * FRAG_ELEMS;

    for (int t = 0; t < 25; ++t) {
        // K fragments for this 32-kv tile (6 x 16B lane-linear loads)
        bf16x8 kf[6];
#pragma unroll
        for (int kkb = 0; kkb < 6; ++kkb)
            kf[kkb] = *reinterpret_cast<const bf16x8*>(
                Kb + ((size_t)(t * 6 + kkb) * 64 + lane) * 8);

        __builtin_amdgcn_s_setprio(1);
        f32x16 sA = zero16(), sB = zero16();
#pragma unroll
        for (int kkb = 0; kkb < 6; ++kkb) {
            sA = __builtin_amdgcn_mfma_f32_32x32x16_bf16(kf[kkb], qfA[kkb], sA, 0, 0, 0);
            sB = __builtin_amdgcn_mfma_f32_32x32x16_bf16(kf[kkb], qfB[kkb], sB, 0, 0, 0);
        }
        __builtin_amdgcn_s_setprio(0);

        // V fragments (issued before softmax VALU to hide L2 latency)
        bf16x8 v0[3], v1[3];
#pragma unroll
        for (int ct = 0; ct < 3; ++ct) {
            v0[ct] = *reinterpret_cast<const bf16x8*>(
                Vb + ((size_t)((2 * t) * 3 + ct) * 64 + lane) * 8);
            v1[ct] = *reinterpret_cast<const bf16x8*>(
                Vb + ((size_t)((2 * t + 1) * 3 + ct) * 64 + lane) * 8);
        }

        // softmax (fixed-m): p = exp2(s) via v_exp, truncated to bf16
        const bool full = (t < 24);
        unsigned dA[8], dB[8], swA[8], swB[8];
        {
            float p[16];
#pragma unroll
            for (int r = 0; r < 16; ++r) {
                float e = __builtin_amdgcn_exp2f(sA[r]);
                p[r] = __builtin_bit_cast(float,
                         __builtin_bit_cast(unsigned, e) & 0xFFFF0000u);
            }
            float a0 = 0.f, a1 = 0.f;
#pragma unroll
            for (int r = 0; r < 8; ++r) { a0 += p[r]; a1 += p[r + 8]; }
            lA += a0 + (full ? a1 : 0.f);
#pragma unroll
            for (int j = 0; j < 8; ++j) dA[j] = pack_trunc(p[2 * j], p[2 * j + 1]);
        }
        {
            float p[16];
#pragma unroll
            for (int r = 0; r < 16; ++r) {
                float e = __builtin_amdgcn_exp2f(sB[r]);
                p[r] = __builtin_bit_cast(float,
                         __builtin_bit_cast(unsigned, e) & 0xFFFF0000u);
            }
            float a0 = 0.f, a1 = 0.f;
#pragma unroll
            for (int r = 0; r < 8; ++r) { a0 += p[r]; a1 += p[r + 8]; }
            lB += a0 + (full ? a1 : 0.f);
#pragma unroll
            for (int j = 0; j < 8; ++j) dB[j] = pack_trunc(p[2 * j], p[2 * j + 1]);
        }
#pragma unroll
        for (int j = 0; j < 8; ++j) {
            swA[j] = (unsigned)__shfl_xor((int)dA[j], 32);
            swB[j] = (unsigned)__shfl_xor((int)dB[j], 32);
        }

        // PV kv-half 0 (kv16 = 2t)
        {
            int4 biA = h ? make_int4((int)swA[2], (int)swA[3], (int)dA[2], (int)dA[3])
                         : make_int4((int)dA[0], (int)dA[1], (int)swA[0], (int)swA[1]);
            int4 biB = h ? make_int4((int)swB[2], (int)swB[3], (int)dB[2], (int)dB[3])
                         : make_int4((int)dB[0], (int)dB[1], (int)swB[0], (int)swB[1]);
            bf16x8 bfA = __builtin_bit_cast(bf16x8, biA);
            bf16x8 bfB = __builtin_bit_cast(bf16x8, biB);
            __builtin_amdgcn_s_setprio(1);
            aA0 = __builtin_amdgcn_mfma_f32_32x32x16_bf16(v0[0], bfA, aA0, 0, 0, 0);
            aB0 = __builtin_amdgcn_mfma_f32_32x32x16_bf16(v0[0], bfB, aB0, 0, 0, 0);
            aA1 = __builtin_amdgcn_mfma_f32_32x32x16_bf16(v0[1], bfA, aA1, 0, 0, 0);
            aB1 = __builtin_amdgcn_mfma_f32_32x32x16_bf16(v0[1], bfB, aB1, 0, 0, 0);
            aA2 = __builtin_amdgcn_mfma_f32_32x32x16_bf16(v0[2], bfA, aA2, 0, 0, 0);
            aB2 = __builtin_amdgcn_mfma_f32_32x32x16_bf16(v0[2], bfB, aB2, 0, 0, 0);
            __builtin_amdgcn_s_setprio(0);
        }
        // PV kv-half 1 (kv16 = 2t+1; tile 24's half 1 is all pad -> skip)
        if (full) {
            int4 biA = h ? make_int4((int)swA[6], (int)swA[7], (int)dA[6], (int)dA[7])
                         : make_int4((int)dA[4], (int)dA[5], (int)swA[4], (int)swA[5]);
            int4 biB = h ? make_int4((int)swB[6], (int)swB[7], (int)dB[6], (int)dB[7])
                         : make_int4((int)dB[4], (int)dB[5], (int)swB[4], (int)swB[5]);
            bf16x8 bfA = __builtin_bit_cast(bf16x8, biA);
            bf16x8 bfB = __builtin_bit_cast(bf16x8, biB);
            __builtin_amdgcn_s_setprio(1);
            aA0 = __builtin_amdgcn_mfma_f32_32x32x16_bf16(v1[0], bfA, aA0, 0, 0, 0);
            aB0 = __builtin_amdgcn_mfma_f32_32x32x16_bf16(v1[0], bfB, aB0, 0, 0, 0);
            aA1 = __builtin_amdgcn_mfma_f32_32x32x16_bf16(v1[1], bfA, aA1, 0, 0, 0);
            aB1 = __builtin_amdgcn_mfma_f32_32x32x16_bf16(v1[1], bfB, aB1, 0, 0, 0);
            aA2 = __builtin_amdgcn_mfma_f32_32x32x16_bf16(v1[2], bfA, aA2, 0, 0, 0);
            aB2 = __builtin_amdgcn_mfma_f32_32x32x16_bf16(v1[2], bfB, aB2, 0, 0, 0);
            __builtin_amdgcn_s_setprio(0);
        }
    }

    lA += __shfl_xor(lA, 32);
    lB += __shfl_xor(lB, 32);
    const float invA = 1.f / lA;
    const float invB = 1.f / lB;

    {
        unsigned short* op = out + ((size_t)b * N_IN + qrowA) * 96;
#pragma unroll
        for (int ct = 0; ct < 3; ++ct) {
            const f32x16& a = (ct == 0) ? aA0 : (ct == 1 ? aA1 : aA2);
#pragma unroll
            for (int gblk = 0; gblk < 4; ++gblk) {
                int ch = ct * 32 + gblk * 8 + 4 * h;
                ushort4 q4 = *reinterpret_cast<const ushort4*>(qptrA + ch);
                uint2 pr;
                pr.x = pack_bf16(a[gblk * 4 + 0] * invA + bf16_to_f32(q4.x),
                                 a[gblk * 4 + 1] * invA + bf16_to_f32(q4.y));
                pr.y = pack_bf16(a[gblk * 4 + 2] * invA + bf16_to_f32(q4.z),
                                 a[gblk * 4 + 3] * invA + bf16_to_f32(q4.w));
                *reinterpret_cast<uint2*>(op + ch) = pr;
            }
        }
    }
    {
        unsigned short* op = out + ((size_t)b * N_IN + qrowB) * 96;
#pragma unroll
        for (int ct = 0; ct < 3; ++ct) {
            const f32x16& a = (ct == 0) ? aB0 : (ct == 1 ? aB1 : aB2);
#pragma unroll
            for (int gblk = 0; gblk < 4; ++gblk) {
                int ch = ct * 32 + gblk * 8 + 4 * h;
                ushort4 q4 = *reinterpret_cast<const ushort4*>(qptrB + ch);
                uint2 pr;
                pr.x = pack_bf16(a[gblk * 4 + 0] * invB + bf16_to_f32(q4.x),
                                 a[gblk * 4 + 1] * invB + bf16_to_f32(q4.y));
                pr.y = pack_bf16(a[gblk * 4 + 2] * invB + bf16_to_f32(q4.z),
                                 a[gblk * 4 + 3] * invB + bf16_to_f32(q4.w));
                *reinterpret_cast<uint2*>(op + ch) = pr;
            }
        }
    }
}

// ---------------------------------------------------------------------------
extern "C" void kernel_launch(void* const* d_in, const int* in_sizes, int n_in,
                              void* d_out, int out_size, void* d_ws, size_t ws_size,
                              hipStream_t stream)
{
    const float* x     = (const float*)d_in[0];
    const float* Wqkv  = (const float*)d_in[1];
    const float* bqkv  = (const float*)d_in[2];
    const float* pqw   = (const float*)d_in[3];
    const float* gq    = (const float*)d_in[4];
    const float* betq  = (const float*)d_in[5];
    const float* pkw   = (const float*)d_in[6];
    const float* gk    = (const float*)d_in[7];
    const float* betk  = (const float*)d_in[8];
    const float* pvw   = (const float*)d_in[9];
    const float* gv    = (const float*)d_in[10];
    const float* betv  = (const float*)d_in[11];
    const float* Wproj = (const float*)d_in[12];
    const float* bproj = (const float*)d_in[13];
    float* outp = (float*)d_out;

    char* ws = (char*)d_ws;
    const size_t QB    = (size_t)BATCH * N_IN * 96 * sizeof(short);       // 19.27 MB
    const size_t FRAGB = (size_t)BATCH * FRAG_ELEMS * sizeof(short);      // 5.31 MB
    unsigned short* qb   = (unsigned short*)(ws);
    unsigned short* kbuf = (unsigned short*)(ws + QB);
    unsigned short* vbuf = (unsigned short*)(ws + 2 * QB);
    unsigned short* qpb  = (unsigned short*)(ws + 3 * QB);
    unsigned short* Kfr  = (unsigned short*)(ws + 4 * QB);
    unsigned short* Vfr  = (unsigned short*)(ws + 4 * QB + FRAGB);
    unsigned short* wqf  = (unsigned short*)(ws + 4 * QB + 2 * FRAGB);
    unsigned short* wpf  = (unsigned short*)(ws + 4 * QB + 2 * FRAGB + 56320);
    float*          wpool = (float*)(ws + 4 * QB + 2 * FRAGB + 56320 + 18432);
    unsigned short* attn_out = qb;   // qb dead after pool_q

    const int T = BATCH * N_IN;      // 100352 = 256 * 392

    const float SC = 0.1020620726159658f * 1.4426950408889634f; // scale*log2e

    // 0. one-time weight prep (GEMM frags + pool transposes)
    wprep_kernel<<<29, 256, 0, stream>>>(Wqkv, Wproj, pqw, pkw, pvw, wqf, wpf, wpool);
    // 1. QKV projection (MFMA) -> q,k,v bf16 [B][3136][96]
    gemm2_kernel<18, false, false><<<T / 256, 256, 0, stream>>>(
        x, wqf, bqkv, qb, kbuf, vbuf);
    // 2-4. pool v4 (conv+LN): q row-major; K/V straight to MFMA-frag order
    pool_ln4_kernel<0, 1><<<T / 16, 192, 0, stream>>>(
        qb, wpool, gq, betq, qpb, 56, 56, N_IN, 1.0f);
    pool_ln4_kernel<1, 2><<<(BATCH * LKV_PAD) / 16, 192, 0, stream>>>(
        kbuf, wpool + 864, gk, betk, Kfr, 28, 28, LKV_PAD, SC);
    pool_ln4_kernel<2, 2><<<(BATCH * LKV_PAD) / 16, 192, 0, stream>>>(
        vbuf, wpool + 1728, gv, betv, Vfr, 28, 28, LKV_PAD, 1.0f);
    // 5. MFMA attention v4 (barrier-free, 1 wave / 64 q) + residual
    attn_mfma4_kernel<<<1568, 64, 0, stream>>>(qpb, Kfr, Vfr, attn_out);
    // 6. output projection (MFMA, fp32 out)
    gemm2_kernel<6, true, true><<<T / 256, 256, 0, stream>>>(
        attn_out, wpf, bproj, outp, nullptr, nullptr);
}

// Round 8
// 153.769 us; speedup vs baseline: 16.5146x; 1.0682x over previous
//
#include <hip/hip_runtime.h>
#include <hip/hip_bf16.h>
#include <cmath>

#define BATCH 32
#define H_IN 56
#define W_IN 56
#define N_IN (H_IN * W_IN)   // 3136
#define LKV 784              // 28*28 pooled kv length
#define LKV_PAD 864          // 27 tiles of 32
#define FRAG_ELEMS 82944     // per-batch K/V frag buffer elems (27*6*512)

typedef short bf16x8 __attribute__((ext_vector_type(8)));
typedef float f32x4 __attribute__((ext_vector_type(4)));
typedef float f32x16 __attribute__((ext_vector_type(16)));

__device__ __forceinline__ unsigned pack_bf16(float a, float b) {
    unsigned ua = __builtin_bit_cast(unsigned, a);
    unsigned ub = __builtin_bit_cast(unsigned, b);
    ua = (ua + 0x7FFFu + ((ua >> 16) & 1u)) >> 16;
    ub = (ub + 0x7FFFu + ((ub >> 16) & 1u)) >> 16;
    return ua | (ub << 16);
}

__device__ __forceinline__ unsigned short cvt_bf16(float a) {
    unsigned ua = __builtin_bit_cast(unsigned, a);
    return (unsigned short)((ua + 0x7FFFu + ((ua >> 16) & 1u)) >> 16);
}

__device__ __forceinline__ float bf16_to_f32(unsigned short u) {
    unsigned v = ((unsigned)u) << 16;
    return __builtin_bit_cast(float, v);
}

__device__ __forceinline__ float bflo(unsigned u) {
    return __builtin_bit_cast(float, u << 16);
}
__device__ __forceinline__ float bfhi(unsigned u) {
    return __builtin_bit_cast(float, u & 0xFFFF0000u);
}

// [lo16 = trunc-bf16(a), hi16 = trunc-bf16(b)] in one v_perm
__device__ __forceinline__ unsigned pack_trunc(float a, float b) {
    return __builtin_amdgcn_perm(__builtin_bit_cast(unsigned, b),
                                 __builtin_bit_cast(unsigned, a), 0x07060302u);
}

__device__ __forceinline__ f32x16 zero16() {
    f32x16 z;
#pragma unroll
    for (int i = 0; i < 16; ++i) z[i] = 0.f;
    return z;
}

// ---------------------------------------------------------------------------
// One-time weight prep:
//  idx <  3456 : Wqkv fp32 [288][96] -> bf16 A-frag order (54 frags)
//  idx <  4608 : Wproj fp32 [96][96] -> bf16 A-frag order (18 frags)
//  idx <  7200 : pool conv weights [96][9] -> transposed fp32 [3][9][96]
// ---------------------------------------------------------------------------
__global__ __launch_bounds__(256) void wprep_kernel(
    const float* __restrict__ Wqkv, const float* __restrict__ Wproj,
    const float* __restrict__ pqw, const float* __restrict__ pkw,
    const float* __restrict__ pvw,
    unsigned short* __restrict__ wq, unsigned short* __restrict__ wp,
    float* __restrict__ wpool)
{
    int idx = blockIdx.x * 256 + threadIdx.x;
    if (idx < 4608) {
        const float* src; unsigned short* dst; int li;
        if (idx < 3456) { src = Wqkv; dst = wq; li = idx; }
        else            { src = Wproj; dst = wp; li = idx - 3456; }
        int frag = li >> 6, ln = li & 63;
        int ct = frag / 3, kkb = frag % 3;
        int ch = ct * 16 + (ln & 15);
        int k0 = kkb * 32 + (ln >> 4) * 8;
        const float* s = src + ch * 96 + k0;
        float4 v0 = *reinterpret_cast<const float4*>(s);
        float4 v1 = *reinterpret_cast<const float4*>(s + 4);
        uint4 o;
        o.x = pack_bf16(v0.x, v0.y); o.y = pack_bf16(v0.z, v0.w);
        o.z = pack_bf16(v1.x, v1.y); o.w = pack_bf16(v1.z, v1.w);
        *reinterpret_cast<uint4*>(dst + (size_t)li * 8) = o;
    } else if (idx < 7200) {
        int li = idx - 4608;               // 0..2591
        int which = li / 864, r = li % 864;
        int tap = r / 96, c = r % 96;
        const float* src = (which == 0) ? pqw : (which == 1 ? pkw : pvw);
        wpool[which * 864 + tap * 96 + c] = src[c * 9 + tap];
    }
}

// ---------------------------------------------------------------------------
// MFMA GEMM v2: out[t][n] = sum_k X[t][k]*W[n][k] + bias[n]
// 256 thr / 4 waves; 256 tokens per block (64/wave = 4 iters x 16).
// ---------------------------------------------------------------------------
template <int NCT, bool IN_BF16, bool OUT_F32>
__global__ __launch_bounds__(256, 2) void gemm2_kernel(
    const void* __restrict__ Xv, const unsigned short* __restrict__ Wfr,
    const float* __restrict__ bias, void* __restrict__ o0,
    void* __restrict__ o1, void* __restrict__ o2)
{
    __shared__ unsigned short Wl[NCT * 192 * 8];
    const int tid = threadIdx.x;
    const int wid = tid >> 6, lane = tid & 63;
    const int lo16 = lane & 15, hi = lane >> 4;

    for (int idx = tid; idx < NCT * 192; idx += 256)
        *reinterpret_cast<int4*>(&Wl[idx * 8]) =
            *reinterpret_cast<const int4*>(Wfr + (size_t)idx * 8);

    const size_t tok0 = (size_t)blockIdx.x * 256 + wid * 64;
    bf16x8 xb[12];
#pragma unroll
    for (int it = 0; it < 4; ++it) {
        size_t t = tok0 + it * 16 + lo16;
#pragma unroll
        for (int kkb = 0; kkb < 3; ++kkb) {
            if constexpr (IN_BF16) {
                xb[it * 3 + kkb] = *reinterpret_cast<const bf16x8*>(
                    (const unsigned short*)Xv + t * 96 + kkb * 32 + hi * 8);
            } else {
                const float* xp = (const float*)Xv + t * 96 + kkb * 32 + hi * 8;
                float4 a = *reinterpret_cast<const float4*>(xp);
                float4 c = *reinterpret_cast<const float4*>(xp + 4);
                uint4 u;
                u.x = pack_bf16(a.x, a.y); u.y = pack_bf16(a.z, a.w);
                u.z = pack_bf16(c.x, c.y); u.w = pack_bf16(c.z, c.w);
                xb[it * 3 + kkb] = __builtin_bit_cast(bf16x8, u);
            }
        }
    }
    __syncthreads();

#pragma unroll
    for (int ct = 0; ct < NCT; ++ct) {
        bf16x8 wf[3];
#pragma unroll
        for (int kkb = 0; kkb < 3; ++kkb)
            wf[kkb] = *reinterpret_cast<const bf16x8*>(&Wl[((ct * 3 + kkb) * 64 + lane) * 8]);
        const int chb = ct * 16 + hi * 4;
        float4 bv = *reinterpret_cast<const float4*>(bias + chb);
#pragma unroll
        for (int it = 0; it < 4; ++it) {
            f32x4 a = (f32x4){0.f, 0.f, 0.f, 0.f};
#pragma unroll
            for (int kkb = 0; kkb < 3; ++kkb)
                a = __builtin_amdgcn_mfma_f32_16x16x32_bf16(wf[kkb], xb[it * 3 + kkb], a, 0, 0, 0);
            size_t t = tok0 + it * 16 + lo16;
            float r0 = a[0] + bv.x, r1 = a[1] + bv.y;
            float r2 = a[2] + bv.z, r3 = a[3] + bv.w;
            if constexpr (OUT_F32) {
                *reinterpret_cast<float4*>((float*)o0 + t * 96 + chb) =
                    make_float4(r0, r1, r2, r3);
            } else {
                unsigned short* ob =
                    (unsigned short*)((ct < 6) ? o0 : (ct < 12 ? o1 : o2));
                int lch = (ct % 6) * 16 + hi * 4;
                uint2 p;
                p.x = pack_bf16(r0, r1);
                p.y = pack_bf16(r2, r3);
                *reinterpret_cast<uint2*>(ob + t * 96 + lch) = p;
            }
        }
    }
}

// ---------------------------------------------------------------------------
// Pool v4: depthwise 3x3 conv (pad 1) + LayerNorm, bf16 in / bf16 out.
// Block = 192 threads = 16 tokens x 12 chunk-threads (8 ch each).
// OMODE 0: row-major [B][Lp][96] (q). OMODE 1: K MFMA-frag order.
// OMODE 2: V^T MFMA-frag order. For OMODE 1/2 the token space is padded to
// LpPad=864/batch; pad tokens write ZERO frags (consumed as masked pads).
// ---------------------------------------------------------------------------
template <int OMODE, int STRIDE>
__global__ __launch_bounds__(192) void pool_ln4_kernel(
    const unsigned short* __restrict__ in, const float* __restrict__ pwt,
    const float* __restrict__ g, const float* __restrict__ beta,
    unsigned short* __restrict__ out, int Hp, int Wp, int LpPad, float oscale)
{
    __shared__ float2 part[192];
    __shared__ float2 mrs[16];
    const int tid = threadIdx.x;
    const int tok_l = tid / 12, c8 = tid % 12;
    const int gt = blockIdx.x * 16 + tok_l;
    const int Lp = Hp * Wp;
    const int b = gt / LpPad, rem = gt % LpPad;
    const bool pad = (rem >= Lp);
    const int yo = rem / Wp, xo = rem % Wp;

    float wt[9][8];
#pragma unroll
    for (int tap = 0; tap < 9; ++tap) {
        float4 w0 = *reinterpret_cast<const float4*>(pwt + tap * 96 + c8 * 8);
        float4 w1 = *reinterpret_cast<const float4*>(pwt + tap * 96 + c8 * 8 + 4);
        wt[tap][0] = w0.x; wt[tap][1] = w0.y; wt[tap][2] = w0.z; wt[tap][3] = w0.w;
        wt[tap][4] = w1.x; wt[tap][5] = w1.y; wt[tap][6] = w1.z; wt[tap][7] = w1.w;
    }

    float acc[8];
#pragma unroll
    for (int j = 0; j < 8; ++j) acc[j] = 0.f;

    const unsigned short* ib = in + (size_t)b * (H_IN * W_IN * 96) + c8 * 8;
#pragma unroll
    for (int dy = 0; dy < 3; ++dy) {
        const int iy = yo * STRIDE + dy - 1;
        if ((unsigned)iy < (unsigned)H_IN) {
#pragma unroll
            for (int dx = 0; dx < 3; ++dx) {
                const int ix = xo * STRIDE + dx - 1;
                if ((unsigned)ix < (unsigned)W_IN) {
                    const int tap = dy * 3 + dx;
                    uint4 d = *reinterpret_cast<const uint4*>(
                        ib + ((size_t)iy * W_IN + ix) * 96);
                    acc[0] += bflo(d.x) * wt[tap][0];
                    acc[1] += bfhi(d.x) * wt[tap][1];
                    acc[2] += bflo(d.y) * wt[tap][2];
                    acc[3] += bfhi(d.y) * wt[tap][3];
                    acc[4] += bflo(d.z) * wt[tap][4];
                    acc[5] += bfhi(d.z) * wt[tap][5];
                    acc[6] += bflo(d.w) * wt[tap][6];
                    acc[7] += bfhi(d.w) * wt[tap][7];
                }
            }
        }
    }

    float s = 0.f, s2 = 0.f;
#pragma unroll
    for (int j = 0; j < 8; ++j) { s += acc[j]; s2 += acc[j] * acc[j]; }
    part[tid] = make_float2(s, s2);
    __syncthreads();
    if (tid < 16) {
        float a = 0.f, q = 0.f;
#pragma unroll
        for (int j = 0; j < 12; ++j) {
            float2 p = part[tid * 12 + j];
            a += p.x; q += p.y;
        }
        float mu = a * (1.f / 96.f);
        float var = q * (1.f / 96.f) - mu * mu;
        mrs[tid] = make_float2(mu, rsqrtf(var + 1e-6f));
    }
    __syncthreads();
    const float mu = mrs[tok_l].x, rstd = mrs[tok_l].y;

    float4 g0 = *reinterpret_cast<const float4*>(g + c8 * 8);
    float4 g1 = *reinterpret_cast<const float4*>(g + c8 * 8 + 4);
    float4 b0 = *reinterpret_cast<const float4*>(beta + c8 * 8);
    float4 b1 = *reinterpret_cast<const float4*>(beta + c8 * 8 + 4);
    float r[8];
    r[0] = (acc[0] - mu) * rstd * (g0.x * oscale) + b0.x * oscale;
    r[1] = (acc[1] - mu) * rstd * (g0.y * oscale) + b0.y * oscale;
    r[2] = (acc[2] - mu) * rstd * (g0.z * oscale) + b0.z * oscale;
    r[3] = (acc[3] - mu) * rstd * (g0.w * oscale) + b0.w * oscale;
    r[4] = (acc[4] - mu) * rstd * (g1.x * oscale) + b1.x * oscale;
    r[5] = (acc[5] - mu) * rstd * (g1.y * oscale) + b1.y * oscale;
    r[6] = (acc[6] - mu) * rstd * (g1.z * oscale) + b1.z * oscale;
    r[7] = (acc[7] - mu) * rstd * (g1.w * oscale) + b1.w * oscale;
    if (OMODE != 0 && pad) {
#pragma unroll
        for (int j = 0; j < 8; ++j) r[j] = 0.f;
    }

    if constexpr (OMODE == 0) {
        uint4 o;
        o.x = pack_bf16(r[0], r[1]); o.y = pack_bf16(r[2], r[3]);
        o.z = pack_bf16(r[4], r[5]); o.w = pack_bf16(r[6], r[7]);
        *reinterpret_cast<uint4*>(out + (size_t)gt * 96 + c8 * 8) = o;
    } else if constexpr (OMODE == 1) {
        // K frag order: frag(t=kv/32, kkb), lane = (kv&31)|(hi<<5); 16B/thread
        int t = rem >> 5, kkb = c8 >> 1, hi = c8 & 1;
        int ln = (rem & 31) | (hi << 5);
        uint4 o;
        o.x = pack_bf16(r[0], r[1]); o.y = pack_bf16(r[2], r[3]);
        o.z = pack_bf16(r[4], r[5]); o.w = pack_bf16(r[6], r[7]);
        *reinterpret_cast<uint4*>(out + (size_t)b * FRAG_ELEMS +
                                  ((size_t)(t * 6 + kkb) * 64 + ln) * 8) = o;
    } else {
        // V^T frag order: frag(kv16, ct), lane=(ch&31)|(lh<<5), elem = kv&7
        int kv16 = rem >> 4, e = rem & 7, lh = (rem >> 3) & 1;
#pragma unroll
        for (int j = 0; j < 8; ++j) {
            int j8 = c8 * 8 + j;
            int ct = j8 >> 5;
            int ln = (j8 & 31) | (lh << 5);
            out[(size_t)b * FRAG_ELEMS + ((size_t)(kv16 * 3 + ct) * 64 + ln) * 8 + e] =
                cvt_bf16(r[j]);
        }
    }
}

// ---------------------------------------------------------------------------
// MFMA flash attention v5 + residual (bf16 out). Barrier-free, one wave
// (64 thr) per 32 q rows -> 3136 independent waves (2x v4's TLP; the
// latency-bound fix). K/V read as lane-linear MFMA fragments straight from
// global (L2-resident, pre-arranged by the pools). No LDS, no syncs.
// Fixed-m softmax via v_exp; KV padded to 864 with zero frags.
// XCD-bijective swizzle: consecutive work within an XCD shares one batch.
// ---------------------------------------------------------------------------
__global__ __launch_bounds__(64) void attn_mfma5_kernel(
    const unsigned short* __restrict__ qpl, const unsigned short* __restrict__ Kf,
    const unsigned short* __restrict__ Vf, unsigned short* __restrict__ out)
{
    const int bid = blockIdx.x;                    // 0..3135
    const int swz = (bid & 7) * 392 + (bid >> 3);  // XCD grouping (3136%8==0)
    const int b = swz / 98, qblk = swz % 98;
    const int lane = threadIdx.x;
    const int l31 = lane & 31, h = lane >> 5;

    const int qrow = qblk * 32 + l31;
    const unsigned short* qptr = qpl + ((size_t)b * N_IN + qrow) * 96;
    bf16x8 qf[6];
#pragma unroll
    for (int kkb = 0; kkb < 6; ++kkb)
        qf[kkb] = *reinterpret_cast<const bf16x8*>(qptr + kkb * 16 + h * 8);

    f32x16 a0 = zero16(), a1 = zero16(), a2 = zero16();
    float lsum = 0.f;

    const unsigned short* Kb = Kf + (size_t)b * FRAG_ELEMS;
    const unsigned short* Vb = Vf + (size_t)b * FRAG_ELEMS;

    for (int t = 0; t < 25; ++t) {
        // K fragments for this 32-kv tile (6 x 16B lane-linear loads)
        bf16x8 kf[6];
#pragma unroll
        for (int kkb = 0; kkb < 6; ++kkb)
            kf[kkb] = *reinterpret_cast<const bf16x8*>(
                Kb + ((size_t)(t * 6 + kkb) * 64 + lane) * 8);

        __builtin_amdgcn_s_setprio(1);
        f32x16 s = zero16();
#pragma unroll
        for (int kkb = 0; kkb < 6; ++kkb)
            s = __builtin_amdgcn_mfma_f32_32x32x16_bf16(kf[kkb], qf[kkb], s, 0, 0, 0);
        __builtin_amdgcn_s_setprio(0);

        // V fragments (issued before softmax VALU to hide L2 latency)
        bf16x8 v0[3], v1[3];
#pragma unroll
        for (int ct = 0; ct < 3; ++ct) {
            v0[ct] = *reinterpret_cast<const bf16x8*>(
                Vb + ((size_t)((2 * t) * 3 + ct) * 64 + lane) * 8);
            v1[ct] = *reinterpret_cast<const bf16x8*>(
                Vb + ((size_t)((2 * t + 1) * 3 + ct) * 64 + lane) * 8);
        }

        // softmax (fixed-m): p = exp2(s) via v_exp, truncated to bf16
        const bool full = (t < 24);
        unsigned d[8], sw[8];
        {
            float p[16];
#pragma unroll
            for (int r = 0; r < 16; ++r) {
                float e = __builtin_amdgcn_exp2f(s[r]);
                p[r] = __builtin_bit_cast(float,
                         __builtin_bit_cast(unsigned, e) & 0xFFFF0000u);
            }
            float q0 = 0.f, q1 = 0.f;
#pragma unroll
            for (int r = 0; r < 8; ++r) { q0 += p[r]; q1 += p[r + 8]; }
            lsum += q0 + (full ? q1 : 0.f);
#pragma unroll
            for (int j = 0; j < 8; ++j) d[j] = pack_trunc(p[2 * j], p[2 * j + 1]);
        }
#pragma unroll
        for (int j = 0; j < 8; ++j)
            sw[j] = (unsigned)__shfl_xor((int)d[j], 32);

        // PV kv-half 0 (kv16 = 2t)
        {
            int4 bi = h ? make_int4((int)sw[2], (int)sw[3], (int)d[2], (int)d[3])
                        : make_int4((int)d[0], (int)d[1], (int)sw[0], (int)sw[1]);
            bf16x8 bf = __builtin_bit_cast(bf16x8, bi);
            __builtin_amdgcn_s_setprio(1);
            a0 = __builtin_amdgcn_mfma_f32_32x32x16_bf16(v0[0], bf, a0, 0, 0, 0);
            a1 = __builtin_amdgcn_mfma_f32_32x32x16_bf16(v0[1], bf, a1, 0, 0, 0);
            a2 = __builtin_amdgcn_mfma_f32_32x32x16_bf16(v0[2], bf, a2, 0, 0, 0);
            __builtin_amdgcn_s_setprio(0);
        }
        // PV kv-half 1 (kv16 = 2t+1; tile 24's half 1 is all pad -> skip)
        if (full) {
            int4 bi = h ? make_int4((int)sw[6], (int)sw[7], (int)d[6], (int)d[7])
                        : make_int4((int)d[4], (int)d[5], (int)sw[4], (int)sw[5]);
            bf16x8 bf = __builtin_bit_cast(bf16x8, bi);
            __builtin_amdgcn_s_setprio(1);
            a0 = __builtin_amdgcn_mfma_f32_32x32x16_bf16(v1[0], bf, a0, 0, 0, 0);
            a1 = __builtin_amdgcn_mfma_f32_32x32x16_bf16(v1[1], bf, a1, 0, 0, 0);
            a2 = __builtin_amdgcn_mfma_f32_32x32x16_bf16(v1[2], bf, a2, 0, 0, 0);
            __builtin_amdgcn_s_setprio(0);
        }
    }

    lsum += __shfl_xor(lsum, 32);
    const float inv = 1.f / lsum;

    unsigned short* op = out + ((size_t)b * N_IN + qrow) * 96;
#pragma unroll
    for (int ct = 0; ct < 3; ++ct) {
        const f32x16& a = (ct == 0) ? a0 : (ct == 1 ? a1 : a2);
#pragma unroll
        for (int gblk = 0; gblk < 4; ++gblk) {
            int ch = ct * 32 + gblk * 8 + 4 * h;
            ushort4 q4 = *reinterpret_cast<const ushort4*>(qptr + ch);
            uint2 pr;
            pr.x = pack_bf16(a[gblk * 4 + 0] * inv + bf16_to_f32(q4.x),
                             a[gblk * 4 + 1] * inv + bf16_to_f32(q4.y));
            pr.y = pack_bf16(a[gblk * 4 + 2] * inv + bf16_to_f32(q4.z),
                             a[gblk * 4 + 3] * inv + bf16_to_f32(q4.w));
            *reinterpret_cast<uint2*>(op + ch) = pr;
        }
    }
}

// ---------------------------------------------------------------------------
extern "C" void kernel_launch(void* const* d_in, const int* in_sizes, int n_in,
                              void* d_out, int out_size, void* d_ws, size_t ws_size,
                              hipStream_t stream)
{
    const float* x     = (const float*)d_in[0];
    const float* Wqkv  = (const float*)d_in[1];
    const float* bqkv  = (const float*)d_in[2];
    const float* pqw   = (const float*)d_in[3];
    const float* gq    = (const float*)d_in[4];
    const float* betq  = (const float*)d_in[5];
    const float* pkw   = (const float*)d_in[6];
    const float* gk    = (const float*)d_in[7];
    const float* betk  = (const float*)d_in[8];
    const float* pvw   = (const float*)d_in[9];
    const float* gv    = (const float*)d_in[10];
    const float* betv  = (const float*)d_in[11];
    const float* Wproj = (const float*)d_in[12];
    const float* bproj = (const float*)d_in[13];
    float* outp = (float*)d_out;

    char* ws = (char*)d_ws;
    const size_t QB    = (size_t)BATCH * N_IN * 96 * sizeof(short);       // 19.27 MB
    const size_t FRAGB = (size_t)BATCH * FRAG_ELEMS * sizeof(short);      // 5.31 MB
    unsigned short* qb   = (unsigned short*)(ws);
    unsigned short* kbuf = (unsigned short*)(ws + QB);
    unsigned short* vbuf = (unsigned short*)(ws + 2 * QB);
    unsigned short* qpb  = (unsigned short*)(ws + 3 * QB);
    unsigned short* Kfr  = (unsigned short*)(ws + 4 * QB);
    unsigned short* Vfr  = (unsigned short*)(ws + 4 * QB + FRAGB);
    unsigned short* wqf  = (unsigned short*)(ws + 4 * QB + 2 * FRAGB);
    unsigned short* wpf  = (unsigned short*)(ws + 4 * QB + 2 * FRAGB + 56320);
    float*          wpool = (float*)(ws + 4 * QB + 2 * FRAGB + 56320 + 18432);
    unsigned short* attn_out = qb;   // qb dead after pool_q

    const int T = BATCH * N_IN;      // 100352 = 256 * 392

    const float SC = 0.1020620726159658f * 1.4426950408889634f; // scale*log2e

    // 0. one-time weight prep (GEMM frags + pool transposes)
    wprep_kernel<<<29, 256, 0, stream>>>(Wqkv, Wproj, pqw, pkw, pvw, wqf, wpf, wpool);
    // 1. QKV projection (MFMA) -> q,k,v bf16 [B][3136][96]
    gemm2_kernel<18, false, false><<<T / 256, 256, 0, stream>>>(
        x, wqf, bqkv, qb, kbuf, vbuf);
    // 2-4. pool v4 (conv+LN): q row-major; K/V straight to MFMA-frag order
    pool_ln4_kernel<0, 1><<<T / 16, 192, 0, stream>>>(
        qb, wpool, gq, betq, qpb, 56, 56, N_IN, 1.0f);
    pool_ln4_kernel<1, 2><<<(BATCH * LKV_PAD) / 16, 192, 0, stream>>>(
        kbuf, wpool + 864, gk, betk, Kfr, 28, 28, LKV_PAD, SC);
    pool_ln4_kernel<2, 2><<<(BATCH * LKV_PAD) / 16, 192, 0, stream>>>(
        vbuf, wpool + 1728, gv, betv, Vfr, 28, 28, LKV_PAD, 1.0f);
    // 5. MFMA attention v5 (barrier-free, 1 wave / 32 q) + residual
    attn_mfma5_kernel<<<3136, 64, 0, stream>>>(qpb, Kfr, Vfr, attn_out);
    // 6. output projection (MFMA, fp32 out)
    gemm2_kernel<6, true, true><<<T / 256, 256, 0, stream>>>(
        attn_out, wpf, bproj, outp, nullptr, nullptr);
}